// Round 1
// baseline (6397.307 us; speedup 1.0000x reference)
//
#include <hip/hip_runtime.h>
#include <hip/hip_bf16.h>
#include <math.h>

// Problem constants
#define BB 4
#define SSEQ 8192
#define HIDDEN 768
#define NH 12
#define DDIM 64
#define KMB 16
#define NMB 512
#define NTOK ((size_t)BB * SSEQ)          // 32768
#define NELT (NTOK * HIDDEN)              // 25,165,824

// ---------------- helpers ----------------
__device__ __forceinline__ float wave_sum(float v) {
#pragma unroll
  for (int off = 32; off > 0; off >>= 1) v += __shfl_xor(v, off, 64);
  return v;
}

__device__ __forceinline__ float gelu_tanh(float x) {
  float x3 = x * x * x;
  return 0.5f * x * (1.0f + tanhf(0.7978845608028654f * (x + 0.044715f * x3)));
}

// ---------------- K1: C(bf16) = A(f32) @ W(f32), optional gelu ----------------
// 64x64 tile, 256 threads, 4x4 acc per thread, K-chunks of 16.
__global__ __launch_bounds__(256) void gemm_xw_bf16(
    const float* __restrict__ A, const float* __restrict__ W,
    __hip_bfloat16* __restrict__ C, int applyGelu) {
  __shared__ __align__(16) float As[16][68];
  __shared__ __align__(16) float Bs[16][68];
  const int tid = threadIdx.x;
  const int m0 = blockIdx.x * 64;
  const int n0 = blockIdx.y * 64;
  const int tm = tid >> 4, tn = tid & 15;
  const int ar = tid >> 2, ac = (tid & 3) << 2;
  const int br = tid >> 4, bc = (tid & 15) << 2;
  float acc[4][4] = {{0.f, 0.f, 0.f, 0.f}, {0.f, 0.f, 0.f, 0.f},
                     {0.f, 0.f, 0.f, 0.f}, {0.f, 0.f, 0.f, 0.f}};
  for (int k0 = 0; k0 < HIDDEN; k0 += 16) {
    const float4 a4 = *(const float4*)(A + (size_t)(m0 + ar) * HIDDEN + k0 + ac);
    const float4 b4 = *(const float4*)(W + (size_t)(k0 + br) * HIDDEN + n0 + bc);
    __syncthreads();
    As[ac + 0][ar] = a4.x; As[ac + 1][ar] = a4.y;
    As[ac + 2][ar] = a4.z; As[ac + 3][ar] = a4.w;
    *(float4*)&Bs[br][bc] = b4;
    __syncthreads();
#pragma unroll
    for (int kk = 0; kk < 16; ++kk) {
      float4 av = *(const float4*)&As[kk][tm << 2];
      float4 bv = *(const float4*)&Bs[kk][tn << 2];
      acc[0][0] += av.x * bv.x; acc[0][1] += av.x * bv.y; acc[0][2] += av.x * bv.z; acc[0][3] += av.x * bv.w;
      acc[1][0] += av.y * bv.x; acc[1][1] += av.y * bv.y; acc[1][2] += av.y * bv.z; acc[1][3] += av.y * bv.w;
      acc[2][0] += av.z * bv.x; acc[2][1] += av.z * bv.y; acc[2][2] += av.z * bv.z; acc[2][3] += av.z * bv.w;
      acc[3][0] += av.w * bv.x; acc[3][1] += av.w * bv.y; acc[3][2] += av.w * bv.z; acc[3][3] += av.w * bv.w;
    }
  }
#pragma unroll
  for (int mi = 0; mi < 4; ++mi) {
    float r0 = acc[mi][0], r1 = acc[mi][1], r2 = acc[mi][2], r3 = acc[mi][3];
    if (applyGelu) {
      r0 = gelu_tanh(r0); r1 = gelu_tanh(r1); r2 = gelu_tanh(r2); r3 = gelu_tanh(r3);
    }
    union { __hip_bfloat16 h[4]; uint2 u; } pk;
    pk.h[0] = __float2bfloat16(r0); pk.h[1] = __float2bfloat16(r1);
    pk.h[2] = __float2bfloat16(r2); pk.h[3] = __float2bfloat16(r3);
    *(uint2*)(C + (size_t)(m0 + (tm << 2) + mi) * HIDDEN + n0 + (tn << 2)) = pk.u;
  }
}

// ---------------- K2: lrpre[b,h,s] = x[b,s,:]·lr_w[h,:] + lr_b[h] ----------------
__global__ __launch_bounds__(256) void lrpre_kernel(
    const float* __restrict__ x, const float* __restrict__ lrw,
    const float* __restrict__ lrb, float* __restrict__ lrpre) {
  const int g = threadIdx.x >> 6, l = threadIdx.x & 63;
  const int t = blockIdx.x * 4 + g;  // global token
  const float* xr = x + (size_t)t * HIDDEN;
  float xv[12];
#pragma unroll
  for (int j = 0; j < 12; ++j) xv[j] = xr[l + 64 * j];
  const int b = t >> 13, s = t & (SSEQ - 1);
  for (int h = 0; h < NH; ++h) {
    const float* wr = lrw + (size_t)h * HIDDEN;
    float a = 0.f;
#pragma unroll
    for (int j = 0; j < 12; ++j) a += xv[j] * wr[l + 64 * j];
    a = wave_sum(a);
    if (l == 0) lrpre[((size_t)b * NH + h) * SSEQ + s] = a + lrb[h];
  }
}

// ---------------- K3: conv (causal, excludes current token) + RoPE ----------------
// One thread per (token, channel-pair). out[t] = b + sum_{kk} w[kk]*in[t-4+kk]
__global__ __launch_bounds__(256) void convrope_kernel(
    const __hip_bfloat16* __restrict__ xqk,
    const float* __restrict__ cqw, const float* __restrict__ cqb,
    const float* __restrict__ ckw, const float* __restrict__ ckb,
    __hip_bfloat16* __restrict__ XQ, __hip_bfloat16* __restrict__ XK) {
  const size_t gid = (size_t)blockIdx.x * 256 + threadIdx.x;  // over NTOK*384
  const int p = (int)(gid % 384);
  const size_t bt = gid / 384;           // global token index
  const int t = (int)(bt & (SSEQ - 1));  // position in sequence
  const int c0 = 2 * p, c1 = c0 + 1;
  float q0 = cqb[c0], q1 = cqb[c1], k0v = ckb[c0], k1v = ckb[c1];
#pragma unroll
  for (int kk = 0; kk < 4; ++kk) {
    const int tp = t - 4 + kk;
    if (tp >= 0) {
      const size_t src = (bt - t + tp) * HIDDEN;
      const float x0 = __bfloat162float(xqk[src + c0]);
      const float x1 = __bfloat162float(xqk[src + c1]);
      q0  += cqw[kk * HIDDEN + c0] * x0;  q1  += cqw[kk * HIDDEN + c1] * x1;
      k0v += ckw[kk * HIDDEN + c0] * x0;  k1v += ckw[kk * HIDDEN + c1] * x1;
    }
  }
  const int f = p & 31;
  const float invf = expf(-(float)f * 0.28782313662425572f);  // ln(10000)/32
  const float ang = (float)t * invf;
  float sn, cs;
  sincosf(ang, &sn, &cs);
  const size_t o = bt * HIDDEN;
  XQ[o + c0] = __float2bfloat16(q0 * cs - q1 * sn);
  XQ[o + c1] = __float2bfloat16(q0 * sn + q1 * cs);
  XK[o + c0] = __float2bfloat16(k0v * cs - k1v * sn);
  XK[o + c1] = __float2bfloat16(k0v * sn + k1v * cs);
}

// ---------------- K4: sequential TTT scan; one block per (b,h) ----------------
// 512 threads = 8 waves. Wave g owns rows {g, g+8} of the 16-token minibatch
// and d-slice [8g, 8g+8) of the W1 state for updates. W1 stored transposed
// (W1T[e][d], pad 68) so k@W1 / q@W1 are float4 LDS reads.
__global__ __launch_bounds__(512) void scan_kernel(
    const __hip_bfloat16* __restrict__ XQ, const __hip_bfloat16* __restrict__ XK,
    const __hip_bfloat16* __restrict__ XV, const float* __restrict__ lrpre,
    const float* __restrict__ lti, const float* __restrict__ tnsg,
    const float* __restrict__ tnbg, const float* __restrict__ W1g,
    const float* __restrict__ b1g, __hip_bfloat16* __restrict__ Z) {
  const int bh = blockIdx.x;
  const int b = bh / NH, h = bh % NH;
  const int tid = threadIdx.x;
  const int g = tid >> 6, l = tid & 63;

  __shared__ __align__(16) float W1T[64][68];
  __shared__ float b1s[64];
  __shared__ __align__(16) float qs[16][68];
  __shared__ __align__(16) float ks[16][68];
  __shared__ __align__(16) float vs[16][68];
  __shared__ __align__(16) float grads[16][68];
  __shared__ float coef[16][17];
  __shared__ float etab[16];
  __shared__ float tok[16];
  __shared__ float tns[64], tnb[64];

  for (int idx = tid; idx < 4096; idx += 512) {
    const int d = idx >> 6, e = idx & 63;
    W1T[e][d] = W1g[(size_t)h * 4096 + idx];
  }
  if (tid < 64) {
    b1s[tid] = b1g[h * 64 + tid];
    tns[tid] = tnsg[h * 64 + tid];
    tnb[tid] = tnbg[h * 64 + tid];
  }
  if (tid < 16) tok[tid] = fmaxf(1.0f / (float)(tid + 1) + lti[tid], 0.0f);
  __syncthreads();

  const size_t baseTok = (size_t)b * SSEQ;
  const int i0 = g, i1 = g + 8;

  for (int mb = 0; mb < NMB; ++mb) {
    const int t0 = mb * KMB;
    // ---- load minibatch ----
    for (int r = g; r < 16; r += 8) {
      const size_t off = (baseTok + t0 + r) * HIDDEN + h * 64 + l;
      qs[r][l] = __bfloat162float(XQ[off]);
      ks[r][l] = __bfloat162float(XK[off]);
      vs[r][l] = __bfloat162float(XV[off]);
    }
    if (tid < 16) {
      const float pre = lrpre[((size_t)b * NH + h) * SSEQ + t0 + tid];
      etab[tid] = (1.0f / 64.0f) / (1.0f + expf(-pre));
    }
    __syncthreads();

    // ---- phase A: Z1 = k@W1+b1 (and q@W1+b1 into regs), LN-bwd grad, Attn coef ----
    float zk0 = b1s[l], zk1 = b1s[l], zq0 = b1s[l], zq1 = b1s[l];
#pragma unroll 4
    for (int d0 = 0; d0 < 64; d0 += 4) {
      const float4 w  = *(const float4*)&W1T[l][d0];
      const float4 ka = *(const float4*)&ks[i0][d0];
      const float4 kb = *(const float4*)&ks[i1][d0];
      const float4 qa = *(const float4*)&qs[i0][d0];
      const float4 qb = *(const float4*)&qs[i1][d0];
      zk0 += ka.x * w.x + ka.y * w.y + ka.z * w.z + ka.w * w.w;
      zk1 += kb.x * w.x + kb.y * w.y + kb.z * w.z + kb.w * w.w;
      zq0 += qa.x * w.x + qa.y * w.y + qa.z * w.z + qa.w * w.w;
      zq1 += qb.x * w.x + qb.y * w.y + qb.z * w.z + qb.w * w.w;
    }
#pragma unroll
    for (int rr = 0; rr < 2; ++rr) {
      const int i = rr ? i1 : i0;
      const float z = rr ? zk1 : zk0;
      const float m = wave_sum(z) * (1.0f / 64.0f);
      const float dz = z - m;
      const float var = wave_sum(dz * dz) * (1.0f / 64.0f);
      const float std_ = sqrtf(var + 1e-5f);
      const float xh = dz / std_;
      const float target = vs[i][l] - ks[i][l];
      const float gx = (xh * tns[l] + tnb[l] - target) * tns[l];
      const float mgx = wave_sum(gx) * (1.0f / 64.0f);
      const float mgxh = wave_sum(gx * xh) * (1.0f / 64.0f);
      grads[i][l] = (gx - mgx - xh * mgxh) / std_;
    }
    // Attn+coef (waves 0-3): coef[i][j] = eta[i][j]*(1 + q_i·k_j) for j<=i
    if (tid < 256) {
      const int ii = tid >> 4, jj = tid & 15;
      float cf = 0.0f;
      if (jj <= ii) {
        float a = 0.f;
#pragma unroll
        for (int d0 = 0; d0 < 64; d0 += 4) {
          const float4 qa = *(const float4*)&qs[ii][d0];
          const float4 kb = *(const float4*)&ks[jj][d0];
          a += qa.x * kb.x + qa.y * kb.y + qa.z * kb.z + qa.w * kb.w;
        }
        cf = tok[ii] * etab[jj] * (1.0f + a);
      }
      coef[ii][jj] = cf;
    }
    __syncthreads();

    // ---- phase B: Z1_bar, output, state update ----
#pragma unroll
    for (int rr = 0; rr < 2; ++rr) {
      const int i = rr ? i1 : i0;
      float zb = rr ? zq1 : zq0;
      for (int j = 0; j <= i; ++j) zb -= coef[i][j] * grads[j][l];
      const float m = wave_sum(zb) * (1.0f / 64.0f);
      const float dz = zb - m;
      const float var = wave_sum(dz * dz) * (1.0f / 64.0f);
      const float r_ = rsqrtf(var + 1e-5f);
      const float o = qs[i][l] + dz * r_ * tns[l] + tnb[l];
      Z[(baseTok + t0 + i) * HIDDEN + h * 64 + l] = __float2bfloat16(o);
    }
    // W1[d][e] -= sum_i k[i][d] * (last_e[i]*grad[i][e]);  b1[e] -= sum_i last_e[i]*grad[i][e]
    const float le_t = tok[15];
    float lg[16];
#pragma unroll
    for (int i = 0; i < 16; ++i) lg[i] = le_t * etab[i] * grads[i][l];
#pragma unroll
    for (int q4 = 0; q4 < 2; ++q4) {
      const int d0 = g * 8 + q4 * 4;
      float4 accv = {0.f, 0.f, 0.f, 0.f};
#pragma unroll
      for (int i = 0; i < 16; ++i) {
        const float4 kk = *(const float4*)&ks[i][d0];
        accv.x += kk.x * lg[i]; accv.y += kk.y * lg[i];
        accv.z += kk.z * lg[i]; accv.w += kk.w * lg[i];
      }
      float4* wp = (float4*)&W1T[l][d0];
      float4 wv4 = *wp;
      wv4.x -= accv.x; wv4.y -= accv.y; wv4.z -= accv.z; wv4.w -= accv.w;
      *wp = wv4;
    }
    if (g == 0) {
      float s_ = 0.f;
#pragma unroll
      for (int i = 0; i < 16; ++i) s_ += lg[i];
      b1s[l] -= s_;
    }
    __syncthreads();
  }
}

// ---------------- K5: per-token mean/rstd over 768 ----------------
__global__ __launch_bounds__(256) void stats_kernel(
    const __hip_bfloat16* __restrict__ Z, float* __restrict__ st) {
  const int g = threadIdx.x >> 6, l = threadIdx.x & 63;
  const int t = blockIdx.x * 4 + g;
  const __hip_bfloat16* zr = Z + (size_t)t * HIDDEN;
  float zv[12];
  float s_ = 0.f;
#pragma unroll
  for (int j = 0; j < 12; ++j) { zv[j] = __bfloat162float(zr[l + 64 * j]); s_ += zv[j]; }
  s_ = wave_sum(s_);
  const float m = s_ * (1.0f / 768.0f);
  float v_ = 0.f;
#pragma unroll
  for (int j = 0; j < 12; ++j) { const float d = zv[j] - m; v_ += d * d; }
  v_ = wave_sum(v_) * (1.0f / 768.0f);
  if (l == 0) { st[2 * t] = m; st[2 * t + 1] = rsqrtf(v_ + 1e-5f); }
}

// ---------------- K6: out = ((Z-mu)*rstd*pns + pnb)*gate @ wo ----------------
__global__ __launch_bounds__(256) void gemm_out_kernel(
    const __hip_bfloat16* __restrict__ Zb, const __hip_bfloat16* __restrict__ gateb,
    const float* __restrict__ st, const float* __restrict__ pns,
    const float* __restrict__ pnb, const float* __restrict__ wo,
    float* __restrict__ out) {
  __shared__ __align__(16) float As[16][68];
  __shared__ __align__(16) float Bs[16][68];
  const int tid = threadIdx.x;
  const int m0 = blockIdx.x * 64;
  const int n0 = blockIdx.y * 64;
  const int tm = tid >> 4, tn = tid & 15;
  const int ar = tid >> 2, ac = (tid & 3) << 2;
  const int br = tid >> 4, bc = (tid & 15) << 2;
  const float mu = st[2 * (m0 + ar)];
  const float rstd = st[2 * (m0 + ar) + 1];
  float acc[4][4] = {{0.f, 0.f, 0.f, 0.f}, {0.f, 0.f, 0.f, 0.f},
                     {0.f, 0.f, 0.f, 0.f}, {0.f, 0.f, 0.f, 0.f}};
  for (int k0 = 0; k0 < HIDDEN; k0 += 16) {
    float av[4];
#pragma unroll
    for (int j = 0; j < 4; ++j) {
      const size_t idx = (size_t)(m0 + ar) * HIDDEN + k0 + ac + j;
      const float zz = __bfloat162float(Zb[idx]);
      const float gg = __bfloat162float(gateb[idx]);
      av[j] = ((zz - mu) * rstd * pns[k0 + ac + j] + pnb[k0 + ac + j]) * gg;
    }
    const float4 b4 = *(const float4*)(wo + (size_t)(k0 + br) * HIDDEN + n0 + bc);
    __syncthreads();
    As[ac + 0][ar] = av[0]; As[ac + 1][ar] = av[1];
    As[ac + 2][ar] = av[2]; As[ac + 3][ar] = av[3];
    *(float4*)&Bs[br][bc] = b4;
    __syncthreads();
#pragma unroll
    for (int kk = 0; kk < 16; ++kk) {
      float4 a4 = *(const float4*)&As[kk][tm << 2];
      float4 b4v = *(const float4*)&Bs[kk][tn << 2];
      acc[0][0] += a4.x * b4v.x; acc[0][1] += a4.x * b4v.y; acc[0][2] += a4.x * b4v.z; acc[0][3] += a4.x * b4v.w;
      acc[1][0] += a4.y * b4v.x; acc[1][1] += a4.y * b4v.y; acc[1][2] += a4.y * b4v.z; acc[1][3] += a4.y * b4v.w;
      acc[2][0] += a4.z * b4v.x; acc[2][1] += a4.z * b4v.y; acc[2][2] += a4.z * b4v.z; acc[2][3] += a4.z * b4v.w;
      acc[3][0] += a4.w * b4v.x; acc[3][1] += a4.w * b4v.y; acc[3][2] += a4.w * b4v.z; acc[3][3] += a4.w * b4v.w;
    }
  }
#pragma unroll
  for (int mi = 0; mi < 4; ++mi) {
    float4 r;
    r.x = acc[mi][0]; r.y = acc[mi][1]; r.z = acc[mi][2]; r.w = acc[mi][3];
    *(float4*)(out + (size_t)(m0 + (tm << 2) + mi) * HIDDEN + n0 + (tn << 2)) = r;
  }
}

// ---------------- launch ----------------
extern "C" void kernel_launch(void* const* d_in, const int* in_sizes, int n_in,
                              void* d_out, int out_size, void* d_ws, size_t ws_size,
                              hipStream_t stream) {
  const float* x   = (const float*)d_in[0];
  const float* wq  = (const float*)d_in[1];
  const float* wv  = (const float*)d_in[2];
  const float* wo  = (const float*)d_in[3];
  const float* wg  = (const float*)d_in[4];
  const float* cqw = (const float*)d_in[5];
  const float* cqb = (const float*)d_in[6];
  const float* ckw = (const float*)d_in[7];
  const float* ckb = (const float*)d_in[8];
  const float* lrw = (const float*)d_in[9];
  const float* lrb = (const float*)d_in[10];
  const float* lti = (const float*)d_in[11];
  const float* tns = (const float*)d_in[12];
  const float* tnb = (const float*)d_in[13];
  const float* pns = (const float*)d_in[14];
  const float* pnb = (const float*)d_in[15];
  const float* W1g = (const float*)d_in[16];
  const float* b1g = (const float*)d_in[17];
  float* out = (float*)d_out;

  // workspace layout (bf16 intermediates): ~304 MB total
  char* ws = (char*)d_ws;
  __hip_bfloat16* xqk  = (__hip_bfloat16*)ws;
  __hip_bfloat16* xv   = xqk  + NELT;
  __hip_bfloat16* gate = xv   + NELT;
  __hip_bfloat16* xq   = gate + NELT;
  __hip_bfloat16* xk   = xq   + NELT;
  __hip_bfloat16* zb   = xk   + NELT;
  float* lrpre = (float*)(zb + NELT);
  float* st    = lrpre + (size_t)BB * NH * SSEQ;

  const dim3 gemmGrid((unsigned)(NTOK / 64), HIDDEN / 64);
  gemm_xw_bf16<<<gemmGrid, 256, 0, stream>>>(x, wq, xqk, 0);
  gemm_xw_bf16<<<gemmGrid, 256, 0, stream>>>(x, wv, xv, 0);
  gemm_xw_bf16<<<gemmGrid, 256, 0, stream>>>(x, wg, gate, 1);
  lrpre_kernel<<<(unsigned)(NTOK / 4), 256, 0, stream>>>(x, lrw, lrb, lrpre);
  convrope_kernel<<<(unsigned)(NTOK * 384 / 256), 256, 0, stream>>>(
      xqk, cqw, cqb, ckw, ckb, xq, xk);
  scan_kernel<<<BB * NH, 512, 0, stream>>>(xq, xk, xv, lrpre, lti, tns, tnb,
                                           W1g, b1g, zb);
  stats_kernel<<<(unsigned)(NTOK / 4), 256, 0, stream>>>(zb, st);
  gemm_out_kernel<<<gemmGrid, 256, 0, stream>>>(zb, gate, st, pns, pnb, wo, out);
}

// Round 2
// 5974.480 us; speedup vs baseline: 1.0708x; 1.0708x over previous
//
#include <hip/hip_runtime.h>
#include <hip/hip_bf16.h>
#include <math.h>

// Problem constants
#define BB 4
#define SSEQ 8192
#define HIDDEN 768
#define NH 12
#define DDIM 64
#define KMB 16
#define NMB 512
#define NTOK ((size_t)BB * SSEQ)          // 32768
#define NELT (NTOK * HIDDEN)              // 25,165,824

// ---------------- helpers ----------------
__device__ __forceinline__ float wave_sum(float v) {
#pragma unroll
  for (int off = 32; off > 0; off >>= 1) v += __shfl_xor(v, off, 64);
  return v;
}

// Two independent reductions with interleaved shuffle chains (ILP halves latency)
__device__ __forceinline__ void wave_sum2(float& a, float& b) {
#pragma unroll
  for (int off = 32; off > 0; off >>= 1) {
    a += __shfl_xor(a, off, 64);
    b += __shfl_xor(b, off, 64);
  }
}

__device__ __forceinline__ float gelu_tanh(float x) {
  float x3 = x * x * x;
  return 0.5f * x * (1.0f + tanhf(0.7978845608028654f * (x + 0.044715f * x3)));
}

// ---------------- K1: C(bf16) = A(f32) @ W(f32), optional gelu ----------------
__global__ __launch_bounds__(256) void gemm_xw_bf16(
    const float* __restrict__ A, const float* __restrict__ W,
    __hip_bfloat16* __restrict__ C, int applyGelu) {
  __shared__ __align__(16) float As[16][68];
  __shared__ __align__(16) float Bs[16][68];
  const int tid = threadIdx.x;
  const int m0 = blockIdx.x * 64;
  const int n0 = blockIdx.y * 64;
  const int tm = tid >> 4, tn = tid & 15;
  const int ar = tid >> 2, ac = (tid & 3) << 2;
  const int br = tid >> 4, bc = (tid & 15) << 2;
  float acc[4][4] = {{0.f, 0.f, 0.f, 0.f}, {0.f, 0.f, 0.f, 0.f},
                     {0.f, 0.f, 0.f, 0.f}, {0.f, 0.f, 0.f, 0.f}};
  for (int k0 = 0; k0 < HIDDEN; k0 += 16) {
    const float4 a4 = *(const float4*)(A + (size_t)(m0 + ar) * HIDDEN + k0 + ac);
    const float4 b4 = *(const float4*)(W + (size_t)(k0 + br) * HIDDEN + n0 + bc);
    __syncthreads();
    As[ac + 0][ar] = a4.x; As[ac + 1][ar] = a4.y;
    As[ac + 2][ar] = a4.z; As[ac + 3][ar] = a4.w;
    *(float4*)&Bs[br][bc] = b4;
    __syncthreads();
#pragma unroll
    for (int kk = 0; kk < 16; ++kk) {
      float4 av = *(const float4*)&As[kk][tm << 2];
      float4 bv = *(const float4*)&Bs[kk][tn << 2];
      acc[0][0] += av.x * bv.x; acc[0][1] += av.x * bv.y; acc[0][2] += av.x * bv.z; acc[0][3] += av.x * bv.w;
      acc[1][0] += av.y * bv.x; acc[1][1] += av.y * bv.y; acc[1][2] += av.y * bv.z; acc[1][3] += av.y * bv.w;
      acc[2][0] += av.z * bv.x; acc[2][1] += av.z * bv.y; acc[2][2] += av.z * bv.z; acc[2][3] += av.z * bv.w;
      acc[3][0] += av.w * bv.x; acc[3][1] += av.w * bv.y; acc[3][2] += av.w * bv.z; acc[3][3] += av.w * bv.w;
    }
  }
#pragma unroll
  for (int mi = 0; mi < 4; ++mi) {
    float r0 = acc[mi][0], r1 = acc[mi][1], r2 = acc[mi][2], r3 = acc[mi][3];
    if (applyGelu) {
      r0 = gelu_tanh(r0); r1 = gelu_tanh(r1); r2 = gelu_tanh(r2); r3 = gelu_tanh(r3);
    }
    union { __hip_bfloat16 h[4]; uint2 u; } pk;
    pk.h[0] = __float2bfloat16(r0); pk.h[1] = __float2bfloat16(r1);
    pk.h[2] = __float2bfloat16(r2); pk.h[3] = __float2bfloat16(r3);
    *(uint2*)(C + (size_t)(m0 + (tm << 2) + mi) * HIDDEN + n0 + (tn << 2)) = pk.u;
  }
}

// ---------------- K2: lrpre[b,h,s] = x[b,s,:]·lr_w[h,:] + lr_b[h] ----------------
__global__ __launch_bounds__(256) void lrpre_kernel(
    const float* __restrict__ x, const float* __restrict__ lrw,
    const float* __restrict__ lrb, float* __restrict__ lrpre) {
  const int g = threadIdx.x >> 6, l = threadIdx.x & 63;
  const int t = blockIdx.x * 4 + g;
  const float* xr = x + (size_t)t * HIDDEN;
  float xv[12];
#pragma unroll
  for (int j = 0; j < 12; ++j) xv[j] = xr[l + 64 * j];
  const int b = t >> 13, s = t & (SSEQ - 1);
  for (int h = 0; h < NH; ++h) {
    const float* wr = lrw + (size_t)h * HIDDEN;
    float a = 0.f;
#pragma unroll
    for (int j = 0; j < 12; ++j) a += xv[j] * wr[l + 64 * j];
    a = wave_sum(a);
    if (l == 0) lrpre[((size_t)b * NH + h) * SSEQ + s] = a + lrb[h];
  }
}

// ---------------- K3: conv (causal, excludes current token) + RoPE ----------------
__global__ __launch_bounds__(256) void convrope_kernel(
    const __hip_bfloat16* __restrict__ xqk,
    const float* __restrict__ cqw, const float* __restrict__ cqb,
    const float* __restrict__ ckw, const float* __restrict__ ckb,
    __hip_bfloat16* __restrict__ XQ, __hip_bfloat16* __restrict__ XK) {
  const size_t gid = (size_t)blockIdx.x * 256 + threadIdx.x;  // over NTOK*384
  const int p = (int)(gid % 384);
  const size_t bt = gid / 384;
  const int t = (int)(bt & (SSEQ - 1));
  const int c0 = 2 * p, c1 = c0 + 1;
  float q0 = cqb[c0], q1 = cqb[c1], k0v = ckb[c0], k1v = ckb[c1];
#pragma unroll
  for (int kk = 0; kk < 4; ++kk) {
    const int tp = t - 4 + kk;
    if (tp >= 0) {
      const size_t src = (bt - t + tp) * HIDDEN;
      const float x0 = __bfloat162float(xqk[src + c0]);
      const float x1 = __bfloat162float(xqk[src + c1]);
      q0  += cqw[kk * HIDDEN + c0] * x0;  q1  += cqw[kk * HIDDEN + c1] * x1;
      k0v += ckw[kk * HIDDEN + c0] * x0;  k1v += ckw[kk * HIDDEN + c1] * x1;
    }
  }
  const int f = p & 31;
  const float invf = expf(-(float)f * 0.28782313662425572f);  // ln(10000)/32
  const float ang = (float)t * invf;
  float sn, cs;
  sincosf(ang, &sn, &cs);
  const size_t o = bt * HIDDEN;
  XQ[o + c0] = __float2bfloat16(q0 * cs - q1 * sn);
  XQ[o + c1] = __float2bfloat16(q0 * sn + q1 * cs);
  XK[o + c0] = __float2bfloat16(k0v * cs - k1v * sn);
  XK[o + c1] = __float2bfloat16(k0v * sn + k1v * cs);
}

// ---------------- K4: sequential TTT scan; one block per (b,h) ----------------
// 512 threads = 8 waves. Wave g owns rows {g, g+8}. W1 transposed in LDS.
// Restructure vs R0: (a) next-minibatch q/k/v/lrpre prefetched into registers
// at top of phase A, written to double-buffered LDS in phase B -> global
// latency off the critical path, 2 barriers/step instead of 3. (b) paired
// shuffle reductions (sum+sumsq, mgx+mgxh). (c) coef work spread over all
// 8 waves (2 lanes per (i,j) cell).
__global__ __launch_bounds__(512) void scan_kernel(
    const __hip_bfloat16* __restrict__ XQ, const __hip_bfloat16* __restrict__ XK,
    const __hip_bfloat16* __restrict__ XV, const float* __restrict__ lrpre,
    const float* __restrict__ lti, const float* __restrict__ tnsg,
    const float* __restrict__ tnbg, const float* __restrict__ W1g,
    const float* __restrict__ b1g, __hip_bfloat16* __restrict__ Z) {
  const int bh = blockIdx.x;
  const int b = bh / NH, h = bh % NH;
  const int tid = threadIdx.x;
  const int g = tid >> 6, l = tid & 63;

  __shared__ __align__(16) float W1T[64][68];
  __shared__ float b1s[64];
  __shared__ __align__(16) float qs[2][16][68];
  __shared__ __align__(16) float ks[2][16][68];
  __shared__ __align__(16) float vs[2][16][68];
  __shared__ __align__(16) float grads[16][68];
  __shared__ float coef[16][17];
  __shared__ float etab[2][16];
  __shared__ float tok[16];
  __shared__ float tns[64], tnb[64];

  for (int idx = tid; idx < 4096; idx += 512) {
    const int d = idx >> 6, e = idx & 63;
    W1T[e][d] = W1g[(size_t)h * 4096 + idx];
  }
  if (tid < 64) {
    b1s[tid] = b1g[h * 64 + tid];
    tns[tid] = tnsg[h * 64 + tid];
    tnb[tid] = tnbg[h * 64 + tid];
  }
  if (tid < 16) tok[tid] = fmaxf(1.0f / (float)(tid + 1) + lti[tid], 0.0f);

  const size_t baseTok = (size_t)b * SSEQ;
  const int i0 = g, i1 = g + 8;
  // coef cell mapping: 2 lanes per (i,j) cell, all 8 waves participate
  const int cc = (g << 5) + (l >> 1);   // cell id in [0,256)
  const int ci = cc >> 4, cj = cc & 15;
  const int chalf = l & 1;              // which half of d

  // prefetch registers
  float pq[2], pk[2], pv[2], plr = 0.f;

  auto load_mb = [&](int mb) {
    const size_t rowbase = (baseTok + (size_t)mb * KMB) * HIDDEN + h * 64 + l;
#pragma unroll
    for (int r = 0; r < 2; ++r) {
      const size_t off = rowbase + (size_t)(g + 8 * r) * HIDDEN;
      pq[r] = __bfloat162float(XQ[off]);
      pk[r] = __bfloat162float(XK[off]);
      pv[r] = __bfloat162float(XV[off]);
    }
    if (tid < 16) plr = lrpre[((size_t)b * NH + h) * SSEQ + (size_t)mb * KMB + tid];
  };
  auto store_mb = [&](int bf) {
#pragma unroll
    for (int r = 0; r < 2; ++r) {
      const int row = g + 8 * r;
      qs[bf][row][l] = pq[r];
      ks[bf][row][l] = pk[r];
      vs[bf][row][l] = pv[r];
    }
    if (tid < 16) etab[bf][tid] = (1.0f / 64.0f) / (1.0f + expf(-plr));
  };

  load_mb(0);
  store_mb(0);
  __syncthreads();

  int buf = 0;
  for (int mb = 0; mb < NMB; ++mb) {
    // issue next minibatch's global loads (consumed in phase B)
    if (mb + 1 < NMB) load_mb(mb + 1);

    // ---- phase A: z = k@W1+b1 (and q@W1+b1), LN-bwd grads, coef ----
    float zk0 = b1s[l], zk1 = b1s[l], zq0 = b1s[l], zq1 = b1s[l];
#pragma unroll 4
    for (int d0 = 0; d0 < 64; d0 += 4) {
      const float4 w  = *(const float4*)&W1T[l][d0];
      const float4 ka = *(const float4*)&ks[buf][i0][d0];
      const float4 kb = *(const float4*)&ks[buf][i1][d0];
      const float4 qa = *(const float4*)&qs[buf][i0][d0];
      const float4 qb = *(const float4*)&qs[buf][i1][d0];
      zk0 += ka.x * w.x + ka.y * w.y + ka.z * w.z + ka.w * w.w;
      zk1 += kb.x * w.x + kb.y * w.y + kb.z * w.z + kb.w * w.w;
      zq0 += qa.x * w.x + qa.y * w.y + qa.z * w.z + qa.w * w.w;
      zq1 += qb.x * w.x + qb.y * w.y + qb.z * w.z + qb.w * w.w;
    }
#pragma unroll
    for (int rr = 0; rr < 2; ++rr) {
      const int i = rr ? i1 : i0;
      const float z = rr ? zk1 : zk0;
      float s1 = z, s2 = z * z;
      wave_sum2(s1, s2);
      const float m = s1 * (1.0f / 64.0f);
      const float var = s2 * (1.0f / 64.0f) - m * m;
      const float std_ = sqrtf(var + 1e-5f);
      const float xh = (z - m) / std_;
      const float target = vs[buf][i][l] - ks[buf][i][l];
      float gx = (xh * tns[l] + tnb[l] - target) * tns[l];
      float t1 = gx, t2 = gx * xh;
      wave_sum2(t1, t2);
      grads[i][l] = (gx - t1 * (1.0f / 64.0f) - xh * (t2 * (1.0f / 64.0f))) / std_;
    }
    // coef[i][j] = tok[i]*etab[j]*(1 + q_i·k_j) for j<=i (0 otherwise)
    {
      float a = 0.f;
      const int dbase = chalf << 5;
#pragma unroll
      for (int d0 = 0; d0 < 32; d0 += 4) {
        const float4 qa = *(const float4*)&qs[buf][ci][dbase + d0];
        const float4 kb = *(const float4*)&ks[buf][cj][dbase + d0];
        a += qa.x * kb.x + qa.y * kb.y + qa.z * kb.z + qa.w * kb.w;
      }
      a += __shfl_xor(a, 1, 64);
      if (chalf == 0)
        coef[ci][cj] = (cj <= ci) ? tok[ci] * etab[buf][cj] * (1.0f + a) : 0.0f;
    }
    __syncthreads();  // barrier A

    // ---- phase B: Z1_bar + output; state update; stage next minibatch ----
#pragma unroll
    for (int rr = 0; rr < 2; ++rr) {
      const int i = rr ? i1 : i0;
      float zb = rr ? zq1 : zq0;
#pragma unroll
      for (int j = 0; j < 16; ++j) zb -= coef[i][j] * grads[j][l];
      float s1 = zb, s2 = zb * zb;
      wave_sum2(s1, s2);
      const float m = s1 * (1.0f / 64.0f);
      const float var = s2 * (1.0f / 64.0f) - m * m;
      const float r_ = rsqrtf(var + 1e-5f);
      const float o = qs[buf][i][l] + (zb - m) * r_ * tns[l] + tnb[l];
      Z[(baseTok + (size_t)mb * KMB + i) * HIDDEN + h * 64 + l] = __float2bfloat16(o);
    }
    // W1T[e][d] -= sum_i k[i][d]*lg[i][e];  b1[e] -= sum_i lg[i][e]
    const float le_t = tok[15];
    float lg[16];
#pragma unroll
    for (int i = 0; i < 16; ++i) lg[i] = le_t * etab[buf][i] * grads[i][l];
#pragma unroll
    for (int q4 = 0; q4 < 2; ++q4) {
      const int d0 = g * 8 + q4 * 4;
      float4 accv = {0.f, 0.f, 0.f, 0.f};
#pragma unroll
      for (int i = 0; i < 16; ++i) {
        const float4 kk = *(const float4*)&ks[buf][i][d0];
        accv.x += kk.x * lg[i]; accv.y += kk.y * lg[i];
        accv.z += kk.z * lg[i]; accv.w += kk.w * lg[i];
      }
      float4* wp = (float4*)&W1T[l][d0];
      float4 wv4 = *wp;
      wv4.x -= accv.x; wv4.y -= accv.y; wv4.z -= accv.z; wv4.w -= accv.w;
      *wp = wv4;
    }
    if (g == 0) {
      float s_ = 0.f;
#pragma unroll
      for (int i = 0; i < 16; ++i) s_ += lg[i];
      b1s[l] -= s_;
    }
    // stage next minibatch into the other buffer
    if (mb + 1 < NMB) store_mb(buf ^ 1);
    __syncthreads();  // barrier B
    buf ^= 1;
  }
}

// ---------------- K5: per-token mean/rstd over 768 ----------------
__global__ __launch_bounds__(256) void stats_kernel(
    const __hip_bfloat16* __restrict__ Z, float* __restrict__ st) {
  const int g = threadIdx.x >> 6, l = threadIdx.x & 63;
  const int t = blockIdx.x * 4 + g;
  const __hip_bfloat16* zr = Z + (size_t)t * HIDDEN;
  float zv[12];
  float s_ = 0.f;
#pragma unroll
  for (int j = 0; j < 12; ++j) { zv[j] = __bfloat162float(zr[l + 64 * j]); s_ += zv[j]; }
  s_ = wave_sum(s_);
  const float m = s_ * (1.0f / 768.0f);
  float v_ = 0.f;
#pragma unroll
  for (int j = 0; j < 12; ++j) { const float d = zv[j] - m; v_ += d * d; }
  v_ = wave_sum(v_) * (1.0f / 768.0f);
  if (l == 0) { st[2 * t] = m; st[2 * t + 1] = rsqrtf(v_ + 1e-5f); }
}

// ---------------- K6: out = ((Z-mu)*rstd*pns + pnb)*gate @ wo ----------------
__global__ __launch_bounds__(256) void gemm_out_kernel(
    const __hip_bfloat16* __restrict__ Zb, const __hip_bfloat16* __restrict__ gateb,
    const float* __restrict__ st, const float* __restrict__ pns,
    const float* __restrict__ pnb, const float* __restrict__ wo,
    float* __restrict__ out) {
  __shared__ __align__(16) float As[16][68];
  __shared__ __align__(16) float Bs[16][68];
  const int tid = threadIdx.x;
  const int m0 = blockIdx.x * 64;
  const int n0 = blockIdx.y * 64;
  const int tm = tid >> 4, tn = tid & 15;
  const int ar = tid >> 2, ac = (tid & 3) << 2;
  const int br = tid >> 4, bc = (tid & 15) << 2;
  const float mu = st[2 * (m0 + ar)];
  const float rstd = st[2 * (m0 + ar) + 1];
  float acc[4][4] = {{0.f, 0.f, 0.f, 0.f}, {0.f, 0.f, 0.f, 0.f},
                     {0.f, 0.f, 0.f, 0.f}, {0.f, 0.f, 0.f, 0.f}};
  for (int k0 = 0; k0 < HIDDEN; k0 += 16) {
    float av[4];
#pragma unroll
    for (int j = 0; j < 4; ++j) {
      const size_t idx = (size_t)(m0 + ar) * HIDDEN + k0 + ac + j;
      const float zz = __bfloat162float(Zb[idx]);
      const float gg = __bfloat162float(gateb[idx]);
      av[j] = ((zz - mu) * rstd * pns[k0 + ac + j] + pnb[k0 + ac + j]) * gg;
    }
    const float4 b4 = *(const float4*)(wo + (size_t)(k0 + br) * HIDDEN + n0 + bc);
    __syncthreads();
    As[ac + 0][ar] = av[0]; As[ac + 1][ar] = av[1];
    As[ac + 2][ar] = av[2]; As[ac + 3][ar] = av[3];
    *(float4*)&Bs[br][bc] = b4;
    __syncthreads();
#pragma unroll
    for (int kk = 0; kk < 16; ++kk) {
      float4 a4 = *(const float4*)&As[kk][tm << 2];
      float4 b4v = *(const float4*)&Bs[kk][tn << 2];
      acc[0][0] += a4.x * b4v.x; acc[0][1] += a4.x * b4v.y; acc[0][2] += a4.x * b4v.z; acc[0][3] += a4.x * b4v.w;
      acc[1][0] += a4.y * b4v.x; acc[1][1] += a4.y * b4v.y; acc[1][2] += a4.y * b4v.z; acc[1][3] += a4.y * b4v.w;
      acc[2][0] += a4.z * b4v.x; acc[2][1] += a4.z * b4v.y; acc[2][2] += a4.z * b4v.z; acc[2][3] += a4.z * b4v.w;
      acc[3][0] += a4.w * b4v.x; acc[3][1] += a4.w * b4v.y; acc[3][2] += a4.w * b4v.z; acc[3][3] += a4.w * b4v.w;
    }
  }
#pragma unroll
  for (int mi = 0; mi < 4; ++mi) {
    float4 r;
    r.x = acc[mi][0]; r.y = acc[mi][1]; r.z = acc[mi][2]; r.w = acc[mi][3];
    *(float4*)(out + (size_t)(m0 + (tm << 2) + mi) * HIDDEN + n0 + (tn << 2)) = r;
  }
}

// ---------------- launch ----------------
extern "C" void kernel_launch(void* const* d_in, const int* in_sizes, int n_in,
                              void* d_out, int out_size, void* d_ws, size_t ws_size,
                              hipStream_t stream) {
  const float* x   = (const float*)d_in[0];
  const float* wq  = (const float*)d_in[1];
  const float* wv  = (const float*)d_in[2];
  const float* wo  = (const float*)d_in[3];
  const float* wg  = (const float*)d_in[4];
  const float* cqw = (const float*)d_in[5];
  const float* cqb = (const float*)d_in[6];
  const float* ckw = (const float*)d_in[7];
  const float* ckb = (const float*)d_in[8];
  const float* lrw = (const float*)d_in[9];
  const float* lrb = (const float*)d_in[10];
  const float* lti = (const float*)d_in[11];
  const float* tns = (const float*)d_in[12];
  const float* tnb = (const float*)d_in[13];
  const float* pns = (const float*)d_in[14];
  const float* pnb = (const float*)d_in[15];
  const float* W1g = (const float*)d_in[16];
  const float* b1g = (const float*)d_in[17];
  float* out = (float*)d_out;

  char* ws = (char*)d_ws;
  __hip_bfloat16* xqk  = (__hip_bfloat16*)ws;
  __hip_bfloat16* xv   = xqk  + NELT;
  __hip_bfloat16* gate = xv   + NELT;
  __hip_bfloat16* xq   = gate + NELT;
  __hip_bfloat16* xk   = xq   + NELT;
  __hip_bfloat16* zb   = xk   + NELT;
  float* lrpre = (float*)(zb + NELT);
  float* st    = lrpre + (size_t)BB * NH * SSEQ;

  const dim3 gemmGrid((unsigned)(NTOK / 64), HIDDEN / 64);
  gemm_xw_bf16<<<gemmGrid, 256, 0, stream>>>(x, wq, xqk, 0);
  gemm_xw_bf16<<<gemmGrid, 256, 0, stream>>>(x, wv, xv, 0);
  gemm_xw_bf16<<<gemmGrid, 256, 0, stream>>>(x, wg, gate, 1);
  lrpre_kernel<<<(unsigned)(NTOK / 4), 256, 0, stream>>>(x, lrw, lrb, lrpre);
  convrope_kernel<<<(unsigned)(NTOK * 384 / 256), 256, 0, stream>>>(
      xqk, cqw, cqb, ckw, ckb, xq, xk);
  scan_kernel<<<BB * NH, 512, 0, stream>>>(xq, xk, xv, lrpre, lti, tns, tnb,
                                           W1g, b1g, zb);
  stats_kernel<<<(unsigned)(NTOK / 4), 256, 0, stream>>>(zb, st);
  gemm_out_kernel<<<gemmGrid, 256, 0, stream>>>(zb, gate, st, pns, pnb, wo, out);
}

// Round 3
// 4402.716 us; speedup vs baseline: 1.4530x; 1.3570x over previous
//
#include <hip/hip_runtime.h>
#include <hip/hip_bf16.h>
#include <math.h>

// Problem constants
#define BB 4
#define SSEQ 8192
#define HIDDEN 768
#define NH 12
#define DDIM 64
#define KMB 16
#define NMB 512
#define NTOK ((size_t)BB * SSEQ)          // 32768
#define NELT (NTOK * HIDDEN)              // 25,165,824

typedef short bf16x8 __attribute__((ext_vector_type(8)));
typedef float f32x4 __attribute__((ext_vector_type(4)));

union frag_u {
  bf16x8 v;
  unsigned u32[4];
  unsigned short u16[8];
};

__device__ __forceinline__ f32x4 mfma16(bf16x8 a, bf16x8 b, f32x4 c) {
  return __builtin_amdgcn_mfma_f32_16x16x32_bf16(a, b, c, 0, 0, 0);
}

// ---------------- helpers ----------------
__device__ __forceinline__ float wave_sum(float v) {
#pragma unroll
  for (int off = 32; off > 0; off >>= 1) v += __shfl_xor(v, off, 64);
  return v;
}

__device__ __forceinline__ unsigned short bf16u(float x) {
  union { float f; unsigned u; } a; a.f = x;
  unsigned r = a.u + 0x7fffu + ((a.u >> 16) & 1u);
  return (unsigned short)(r >> 16);
}
__device__ __forceinline__ float bf2f(unsigned short s) {
  union { unsigned u; float f; } a; a.u = ((unsigned)s) << 16; return a.f;
}

__device__ __forceinline__ float gelu_tanh(float x) {
  float x3 = x * x * x;
  return 0.5f * x * (1.0f + tanhf(0.7978845608028654f * (x + 0.044715f * x3)));
}

// ---------------- K1: C(bf16) = A(f32) @ W(f32), optional gelu ----------------
__global__ __launch_bounds__(256) void gemm_xw_bf16(
    const float* __restrict__ A, const float* __restrict__ W,
    __hip_bfloat16* __restrict__ C, int applyGelu) {
  __shared__ __align__(16) float As[16][68];
  __shared__ __align__(16) float Bs[16][68];
  const int tid = threadIdx.x;
  const int m0 = blockIdx.x * 64;
  const int n0 = blockIdx.y * 64;
  const int tm = tid >> 4, tn = tid & 15;
  const int ar = tid >> 2, ac = (tid & 3) << 2;
  const int br = tid >> 4, bc = (tid & 15) << 2;
  float acc[4][4] = {{0.f, 0.f, 0.f, 0.f}, {0.f, 0.f, 0.f, 0.f},
                     {0.f, 0.f, 0.f, 0.f}, {0.f, 0.f, 0.f, 0.f}};
  for (int k0 = 0; k0 < HIDDEN; k0 += 16) {
    const float4 a4 = *(const float4*)(A + (size_t)(m0 + ar) * HIDDEN + k0 + ac);
    const float4 b4 = *(const float4*)(W + (size_t)(k0 + br) * HIDDEN + n0 + bc);
    __syncthreads();
    As[ac + 0][ar] = a4.x; As[ac + 1][ar] = a4.y;
    As[ac + 2][ar] = a4.z; As[ac + 3][ar] = a4.w;
    *(float4*)&Bs[br][bc] = b4;
    __syncthreads();
#pragma unroll
    for (int kk = 0; kk < 16; ++kk) {
      float4 av = *(const float4*)&As[kk][tm << 2];
      float4 bv = *(const float4*)&Bs[kk][tn << 2];
      acc[0][0] += av.x * bv.x; acc[0][1] += av.x * bv.y; acc[0][2] += av.x * bv.z; acc[0][3] += av.x * bv.w;
      acc[1][0] += av.y * bv.x; acc[1][1] += av.y * bv.y; acc[1][2] += av.y * bv.z; acc[1][3] += av.y * bv.w;
      acc[2][0] += av.z * bv.x; acc[2][1] += av.z * bv.y; acc[2][2] += av.z * bv.z; acc[2][3] += av.z * bv.w;
      acc[3][0] += av.w * bv.x; acc[3][1] += av.w * bv.y; acc[3][2] += av.w * bv.z; acc[3][3] += av.w * bv.w;
    }
  }
#pragma unroll
  for (int mi = 0; mi < 4; ++mi) {
    float r0 = acc[mi][0], r1 = acc[mi][1], r2 = acc[mi][2], r3 = acc[mi][3];
    if (applyGelu) {
      r0 = gelu_tanh(r0); r1 = gelu_tanh(r1); r2 = gelu_tanh(r2); r3 = gelu_tanh(r3);
    }
    union { __hip_bfloat16 h[4]; uint2 u; } pk;
    pk.h[0] = __float2bfloat16(r0); pk.h[1] = __float2bfloat16(r1);
    pk.h[2] = __float2bfloat16(r2); pk.h[3] = __float2bfloat16(r3);
    *(uint2*)(C + (size_t)(m0 + (tm << 2) + mi) * HIDDEN + n0 + (tn << 2)) = pk.u;
  }
}

// ---------------- K2: lrpre[b,h,s] = x[b,s,:]·lr_w[h,:] + lr_b[h] ----------------
__global__ __launch_bounds__(256) void lrpre_kernel(
    const float* __restrict__ x, const float* __restrict__ lrw,
    const float* __restrict__ lrb, float* __restrict__ lrpre) {
  const int g = threadIdx.x >> 6, l = threadIdx.x & 63;
  const int t = blockIdx.x * 4 + g;
  const float* xr = x + (size_t)t * HIDDEN;
  float xv[12];
#pragma unroll
  for (int j = 0; j < 12; ++j) xv[j] = xr[l + 64 * j];
  const int b = t >> 13, s = t & (SSEQ - 1);
  for (int h = 0; h < NH; ++h) {
    const float* wr = lrw + (size_t)h * HIDDEN;
    float a = 0.f;
#pragma unroll
    for (int j = 0; j < 12; ++j) a += xv[j] * wr[l + 64 * j];
    a = wave_sum(a);
    if (l == 0) lrpre[((size_t)b * NH + h) * SSEQ + s] = a + lrb[h];
  }
}

// ---------------- K3: conv (causal, excludes current token) + RoPE ----------------
__global__ __launch_bounds__(256) void convrope_kernel(
    const __hip_bfloat16* __restrict__ xqk,
    const float* __restrict__ cqw, const float* __restrict__ cqb,
    const float* __restrict__ ckw, const float* __restrict__ ckb,
    __hip_bfloat16* __restrict__ XQ, __hip_bfloat16* __restrict__ XK) {
  const size_t gid = (size_t)blockIdx.x * 256 + threadIdx.x;  // over NTOK*384
  const int p = (int)(gid % 384);
  const size_t bt = gid / 384;
  const int t = (int)(bt & (SSEQ - 1));
  const int c0 = 2 * p, c1 = c0 + 1;
  float q0 = cqb[c0], q1 = cqb[c1], k0v = ckb[c0], k1v = ckb[c1];
#pragma unroll
  for (int kk = 0; kk < 4; ++kk) {
    const int tp = t - 4 + kk;
    if (tp >= 0) {
      const size_t src = (bt - t + tp) * HIDDEN;
      const float x0 = __bfloat162float(xqk[src + c0]);
      const float x1 = __bfloat162float(xqk[src + c1]);
      q0  += cqw[kk * HIDDEN + c0] * x0;  q1  += cqw[kk * HIDDEN + c1] * x1;
      k0v += ckw[kk * HIDDEN + c0] * x0;  k1v += ckw[kk * HIDDEN + c1] * x1;
    }
  }
  const int f = p & 31;
  const float invf = expf(-(float)f * 0.28782313662425572f);  // ln(10000)/32
  const float ang = (float)t * invf;
  float sn, cs;
  sincosf(ang, &sn, &cs);
  const size_t o = bt * HIDDEN;
  XQ[o + c0] = __float2bfloat16(q0 * cs - q1 * sn);
  XQ[o + c1] = __float2bfloat16(q0 * sn + q1 * cs);
  XK[o + c0] = __float2bfloat16(k0v * cs - k1v * sn);
  XK[o + c1] = __float2bfloat16(k0v * sn + k1v * cs);
}

// ---------------- K4: single-wave MFMA TTT scan; one block (64 thr) per (b,h) ----
// W1 state: 16 fp32 MFMA accumulators W1acc[dblk][eblk], lane(g16,n) holds
// W1[16*dblk + 4*g16 + reg][16*eblk + n]. d-order inside A/B K-positions is the
// permutation sigma(32c+8q+j) = 16*(2c+(j>>2)) + 4q + (j&3), which makes the
// C-layout of the rank-16 update MFMA coincide with the B-operand layout of the
// next step's z-MFMAs (zero-shuffle state recycling). K=16 contractions
// (coef@grads, k^T@lg) pack real data into j<4, zeros into j>=4.
struct ScanBuf {
  uint2 qa[2][2], ka[2][2];                 // A-frag halves (8B each)
  unsigned short kc[4][4], vc[4][4], qc[4][4];  // C-layout gathers
  float lr[4];
};

__global__ __launch_bounds__(64) void scan_mfma_kernel(
    const __hip_bfloat16* __restrict__ XQg, const __hip_bfloat16* __restrict__ XKg,
    const __hip_bfloat16* __restrict__ XVg, const float* __restrict__ lrpre,
    const float* __restrict__ lti, const float* __restrict__ tnsg,
    const float* __restrict__ tnbg, const float* __restrict__ W1g,
    const float* __restrict__ b1g, __hip_bfloat16* __restrict__ Zg) {
  const int bh = blockIdx.x;
  const int b = bh / NH, h = bh % NH;
  const int lane = threadIdx.x;
  const int n = lane & 15, g16 = lane >> 4;
  const float inv64 = 1.0f / 64.0f;

  const unsigned short* XQb = (const unsigned short*)XQg + (size_t)b * SSEQ * HIDDEN + h * 64;
  const unsigned short* XKb = (const unsigned short*)XKg + (size_t)b * SSEQ * HIDDEN + h * 64;
  const unsigned short* XVb = (const unsigned short*)XVg + (size_t)b * SSEQ * HIDDEN + h * 64;
  unsigned short* Zb = (unsigned short*)Zg + (size_t)b * SSEQ * HIDDEN + h * 64;
  const float* lrp = lrpre + ((size_t)b * NH + h) * SSEQ;

  // ---- persistent state ----
  f32x4 W1acc[4][4];
#pragma unroll
  for (int db = 0; db < 4; ++db)
#pragma unroll
    for (int eb = 0; eb < 4; ++eb)
#pragma unroll
      for (int r = 0; r < 4; ++r)
        W1acc[db][eb][r] = W1g[(size_t)h * 4096 + (16 * db + 4 * g16 + r) * 64 + 16 * eb + n];

  float b1r[4], tnsr[4], tnbr[4];
#pragma unroll
  for (int eb = 0; eb < 4; ++eb) {
    const int e = h * 64 + 16 * eb + n;
    b1r[eb] = b1g[e]; tnsr[eb] = tnsg[e]; tnbr[eb] = tnbg[e];
  }
  const float tok_n = fmaxf(1.0f / (float)(n + 1) + lti[n], 0.0f);
  const float tok15 = __shfl(tok_n, 15, 64);

  // ---- lane-constant address offsets (element units) ----
  int offA[2][2], offC[4][4];
#pragma unroll
  for (int c = 0; c < 2; ++c)
#pragma unroll
    for (int jg = 0; jg < 2; ++jg)
      offA[c][jg] = n * HIDDEN + 16 * (2 * c + jg) + 4 * g16;
#pragma unroll
  for (int blk = 0; blk < 4; ++blk)
#pragma unroll
    for (int r = 0; r < 4; ++r)
      offC[blk][r] = (4 * g16 + r) * HIDDEN + 16 * blk + n;

  auto load_mb = [&](ScanBuf& bf, int mb) {
    const size_t sb = (size_t)mb * (KMB * HIDDEN);
#pragma unroll
    for (int c = 0; c < 2; ++c)
#pragma unroll
      for (int jg = 0; jg < 2; ++jg) {
        bf.qa[c][jg] = *(const uint2*)(XQb + sb + offA[c][jg]);
        bf.ka[c][jg] = *(const uint2*)(XKb + sb + offA[c][jg]);
      }
#pragma unroll
    for (int blk = 0; blk < 4; ++blk)
#pragma unroll
      for (int r = 0; r < 4; ++r) {
        bf.kc[blk][r] = XKb[sb + offC[blk][r]];
        bf.vc[blk][r] = XVb[sb + offC[blk][r]];
        bf.qc[blk][r] = XQb[sb + offC[blk][r]];
      }
    const float4 l4 = *(const float4*)(lrp + mb * KMB + 4 * g16);
    bf.lr[0] = l4.x; bf.lr[1] = l4.y; bf.lr[2] = l4.z; bf.lr[3] = l4.w;
  };

  auto compute_mb = [&](ScanBuf& bf, int mb) {
    const size_t sb = (size_t)mb * (KMB * HIDDEN);
    // eta for this wave's 4 j-tokens (j = 4*g16 + jj)
    float etaj[4];
#pragma unroll
    for (int jj = 0; jj < 4; ++jj)
      etaj[jj] = 1.0f / (64.0f * (1.0f + __expf(-bf.lr[jj])));

    // W1 -> bf16 B-frags (pure per-lane cvt; layout identity)
    frag_u w1f[2][4];
#pragma unroll
    for (int c = 0; c < 2; ++c)
#pragma unroll
      for (int eb = 0; eb < 4; ++eb)
#pragma unroll
        for (int j = 0; j < 4; ++j) {
          w1f[c][eb].u16[j]     = bf16u(W1acc[2 * c][eb][j]);
          w1f[c][eb].u16[4 + j] = bf16u(W1acc[2 * c + 1][eb][j]);
        }
    // A-frags
    frag_u kaf[2], qaf[2];
#pragma unroll
    for (int c = 0; c < 2; ++c) {
      kaf[c].u32[0] = bf.ka[c][0].x; kaf[c].u32[1] = bf.ka[c][0].y;
      kaf[c].u32[2] = bf.ka[c][1].x; kaf[c].u32[3] = bf.ka[c][1].y;
      qaf[c].u32[0] = bf.qa[c][0].x; qaf[c].u32[1] = bf.qa[c][0].y;
      qaf[c].u32[2] = bf.qa[c][1].x; qaf[c].u32[3] = bf.qa[c][1].y;
    }
    // zk = k@W1 + b1 ; zq = q@W1 + b1
    f32x4 zk[4], zq[4];
#pragma unroll
    for (int eb = 0; eb < 4; ++eb) {
      f32x4 init; init[0] = b1r[eb]; init[1] = b1r[eb]; init[2] = b1r[eb]; init[3] = b1r[eb];
      zk[eb] = init; zq[eb] = init;
    }
#pragma unroll
    for (int c = 0; c < 2; ++c)
#pragma unroll
      for (int eb = 0; eb < 4; ++eb) {
        zk[eb] = mfma16(kaf[c].v, w1f[c][eb].v, zk[eb]);
        zq[eb] = mfma16(qaf[c].v, w1f[c][eb].v, zq[eb]);
      }
    // S^T = k @ q^T : lane(g16,n) reg jj = Attn[i=n][j=4*g16+jj]
    f32x4 st_; st_[0] = 0.f; st_[1] = 0.f; st_[2] = 0.f; st_[3] = 0.f;
    st_ = mfma16(kaf[0].v, qaf[0].v, st_);
    st_ = mfma16(kaf[1].v, qaf[1].v, st_);

    // ---- LN-l2-bwd grads from zk ----
    float s1[4], s2[4];
#pragma unroll
    for (int r = 0; r < 4; ++r) {
      s1[r] = zk[0][r] + zk[1][r] + zk[2][r] + zk[3][r];
      s2[r] = zk[0][r] * zk[0][r] + zk[1][r] * zk[1][r] + zk[2][r] * zk[2][r] + zk[3][r] * zk[3][r];
    }
#pragma unroll
    for (int off = 1; off < 16; off <<= 1)
#pragma unroll
      for (int r = 0; r < 4; ++r) {
        s1[r] += __shfl_xor(s1[r], off, 64);
        s2[r] += __shfl_xor(s2[r], off, 64);
      }
    float mr[4], rstd[4];
#pragma unroll
    for (int r = 0; r < 4; ++r) {
      mr[r] = s1[r] * inv64;
      rstd[r] = rsqrtf(s2[r] * inv64 - mr[r] * mr[r] + 1e-5f);
    }
    float xh[4][4], gx[4][4], t1[4] = {0.f, 0.f, 0.f, 0.f}, t2[4] = {0.f, 0.f, 0.f, 0.f};
#pragma unroll
    for (int eb = 0; eb < 4; ++eb)
#pragma unroll
      for (int r = 0; r < 4; ++r) {
        const float xh_ = (zk[eb][r] - mr[r]) * rstd[r];
        const float tg = bf2f(bf.vc[eb][r]) - bf2f(bf.kc[eb][r]);
        const float gx_ = (xh_ * tnsr[eb] + tnbr[eb] - tg) * tnsr[eb];
        xh[eb][r] = xh_; gx[eb][r] = gx_;
        t1[r] += gx_; t2[r] += gx_ * xh_;
      }
#pragma unroll
    for (int off = 1; off < 16; off <<= 1)
#pragma unroll
      for (int r = 0; r < 4; ++r) {
        t1[r] += __shfl_xor(t1[r], off, 64);
        t2[r] += __shfl_xor(t2[r], off, 64);
      }
    float g_[4][4];
#pragma unroll
    for (int eb = 0; eb < 4; ++eb)
#pragma unroll
      for (int r = 0; r < 4; ++r)
        g_[eb][r] = (gx[eb][r] - t1[r] * inv64 - xh[eb][r] * (t2[r] * inv64)) * rstd[r];

    // grads B-frags (j<4 = own C regs; j>=4 zero)
    frag_u gbf[4];
#pragma unroll
    for (int eb = 0; eb < 4; ++eb)
#pragma unroll
      for (int j = 0; j < 4; ++j) {
        gbf[eb].u16[j] = bf16u(g_[eb][j]);
        gbf[eb].u16[4 + j] = 0;
      }
    // coef A-frag: m=i=n, K-pos (g16,jj) -> j-token 4*g16+jj; negated, masked j<=i
    frag_u coef;
#pragma unroll
    for (int jj = 0; jj < 4; ++jj) {
      const int j = 4 * g16 + jj;
      const float cf = (j <= n) ? -tok_n * etaj[jj] * (1.0f + st_[jj]) : 0.0f;
      coef.u16[jj] = bf16u(cf);
      coef.u16[4 + jj] = 0;
    }
    // Z1_bar = zq - coef@grads (coef pre-negated)
    f32x4 zbv[4];
#pragma unroll
    for (int eb = 0; eb < 4; ++eb)
      zbv[eb] = mfma16(coef.v, gbf[eb].v, zq[eb]);

    // ---- output LN + store ----
#pragma unroll
    for (int r = 0; r < 4; ++r) {
      s1[r] = zbv[0][r] + zbv[1][r] + zbv[2][r] + zbv[3][r];
      s2[r] = zbv[0][r] * zbv[0][r] + zbv[1][r] * zbv[1][r] + zbv[2][r] * zbv[2][r] + zbv[3][r] * zbv[3][r];
    }
#pragma unroll
    for (int off = 1; off < 16; off <<= 1)
#pragma unroll
      for (int r = 0; r < 4; ++r) {
        s1[r] += __shfl_xor(s1[r], off, 64);
        s2[r] += __shfl_xor(s2[r], off, 64);
      }
#pragma unroll
    for (int r = 0; r < 4; ++r) {
      mr[r] = s1[r] * inv64;
      rstd[r] = rsqrtf(s2[r] * inv64 - mr[r] * mr[r] + 1e-5f);
    }
#pragma unroll
    for (int eb = 0; eb < 4; ++eb)
#pragma unroll
      for (int r = 0; r < 4; ++r) {
        const float o = bf2f(bf.qc[eb][r]) + (zbv[eb][r] - mr[r]) * rstd[r] * tnsr[eb] + tnbr[eb];
        Zb[sb + offC[eb][r]] = bf16u(o);
      }

    // ---- state update: W1 -= k^T @ (tok15*eta*grads) ; b1 -= sum ----
    float lgv[4][4];
    frag_u lgf[4], ktf[4];
#pragma unroll
    for (int eb = 0; eb < 4; ++eb)
#pragma unroll
      for (int jj = 0; jj < 4; ++jj) {
        lgv[eb][jj] = -tok15 * etaj[jj] * g_[eb][jj];
        lgf[eb].u16[jj] = bf16u(lgv[eb][jj]);
        lgf[eb].u16[4 + jj] = 0;
      }
#pragma unroll
    for (int mk = 0; mk < 4; ++mk)
#pragma unroll
      for (int jj = 0; jj < 4; ++jj) {
        ktf[mk].u16[jj] = bf.kc[mk][jj];
        ktf[mk].u16[4 + jj] = 0;
      }
#pragma unroll
    for (int mk = 0; mk < 4; ++mk)
#pragma unroll
      for (int eb = 0; eb < 4; ++eb)
        W1acc[mk][eb] = mfma16(ktf[mk].v, lgf[eb].v, W1acc[mk][eb]);
#pragma unroll
    for (int eb = 0; eb < 4; ++eb) {
      float s = lgv[eb][0] + lgv[eb][1] + lgv[eb][2] + lgv[eb][3];
      s += __shfl_xor(s, 16, 64);
      s += __shfl_xor(s, 32, 64);
      b1r[eb] += s;
    }
  };

  // ---- main loop: register double-buffer, unroll-by-2, no barriers ----
  ScanBuf A, B;
  load_mb(A, 0);
  for (int mb = 0; mb < NMB; mb += 2) {
    load_mb(B, mb + 1);
    compute_mb(A, mb);
    if (mb + 2 < NMB) load_mb(A, mb + 2);
    compute_mb(B, mb + 1);
  }
}

// ---------------- K5: per-token mean/rstd over 768 ----------------
__global__ __launch_bounds__(256) void stats_kernel(
    const __hip_bfloat16* __restrict__ Z, float* __restrict__ st) {
  const int g = threadIdx.x >> 6, l = threadIdx.x & 63;
  const int t = blockIdx.x * 4 + g;
  const __hip_bfloat16* zr = Z + (size_t)t * HIDDEN;
  float zv[12];
  float s_ = 0.f;
#pragma unroll
  for (int j = 0; j < 12; ++j) { zv[j] = __bfloat162float(zr[l + 64 * j]); s_ += zv[j]; }
  s_ = wave_sum(s_);
  const float m = s_ * (1.0f / 768.0f);
  float v_ = 0.f;
#pragma unroll
  for (int j = 0; j < 12; ++j) { const float d = zv[j] - m; v_ += d * d; }
  v_ = wave_sum(v_) * (1.0f / 768.0f);
  if (l == 0) { st[2 * t] = m; st[2 * t + 1] = rsqrtf(v_ + 1e-5f); }
}

// ---------------- K6: out = ((Z-mu)*rstd*pns + pnb)*gate @ wo ----------------
__global__ __launch_bounds__(256) void gemm_out_kernel(
    const __hip_bfloat16* __restrict__ Zb, const __hip_bfloat16* __restrict__ gateb,
    const float* __restrict__ st, const float* __restrict__ pns,
    const float* __restrict__ pnb, const float* __restrict__ wo,
    float* __restrict__ out) {
  __shared__ __align__(16) float As[16][68];
  __shared__ __align__(16) float Bs[16][68];
  const int tid = threadIdx.x;
  const int m0 = blockIdx.x * 64;
  const int n0 = blockIdx.y * 64;
  const int tm = tid >> 4, tn = tid & 15;
  const int ar = tid >> 2, ac = (tid & 3) << 2;
  const int br = tid >> 4, bc = (tid & 15) << 2;
  const float mu = st[2 * (m0 + ar)];
  const float rstd = st[2 * (m0 + ar) + 1];
  float acc[4][4] = {{0.f, 0.f, 0.f, 0.f}, {0.f, 0.f, 0.f, 0.f},
                     {0.f, 0.f, 0.f, 0.f}, {0.f, 0.f, 0.f, 0.f}};
  for (int k0 = 0; k0 < HIDDEN; k0 += 16) {
    float av[4];
#pragma unroll
    for (int j = 0; j < 4; ++j) {
      const size_t idx = (size_t)(m0 + ar) * HIDDEN + k0 + ac + j;
      const float zz = __bfloat162float(Zb[idx]);
      const float gg = __bfloat162float(gateb[idx]);
      av[j] = ((zz - mu) * rstd * pns[k0 + ac + j] + pnb[k0 + ac + j]) * gg;
    }
    const float4 b4 = *(const float4*)(wo + (size_t)(k0 + br) * HIDDEN + n0 + bc);
    __syncthreads();
    As[ac + 0][ar] = av[0]; As[ac + 1][ar] = av[1];
    As[ac + 2][ar] = av[2]; As[ac + 3][ar] = av[3];
    *(float4*)&Bs[br][bc] = b4;
    __syncthreads();
#pragma unroll
    for (int kk = 0; kk < 16; ++kk) {
      float4 a4 = *(const float4*)&As[kk][tm << 2];
      float4 b4v = *(const float4*)&Bs[kk][tn << 2];
      acc[0][0] += a4.x * b4v.x; acc[0][1] += a4.x * b4v.y; acc[0][2] += a4.x * b4v.z; acc[0][3] += a4.x * b4v.w;
      acc[1][0] += a4.y * b4v.x; acc[1][1] += a4.y * b4v.y; acc[1][2] += a4.y * b4v.z; acc[1][3] += a4.y * b4v.w;
      acc[2][0] += a4.z * b4v.x; acc[2][1] += a4.z * b4v.y; acc[2][2] += a4.z * b4v.z; acc[2][3] += a4.z * b4v.w;
      acc[3][0] += a4.w * b4v.x; acc[3][1] += a4.w * b4v.y; acc[3][2] += a4.w * b4v.z; acc[3][3] += a4.w * b4v.w;
    }
  }
#pragma unroll
  for (int mi = 0; mi < 4; ++mi) {
    float4 r;
    r.x = acc[mi][0]; r.y = acc[mi][1]; r.z = acc[mi][2]; r.w = acc[mi][3];
    *(float4*)(out + (size_t)(m0 + (tm << 2) + mi) * HIDDEN + n0 + (tn << 2)) = r;
  }
}

// ---------------- launch ----------------
extern "C" void kernel_launch(void* const* d_in, const int* in_sizes, int n_in,
                              void* d_out, int out_size, void* d_ws, size_t ws_size,
                              hipStream_t stream) {
  const float* x   = (const float*)d_in[0];
  const float* wq  = (const float*)d_in[1];
  const float* wv  = (const float*)d_in[2];
  const float* wo  = (const float*)d_in[3];
  const float* wg  = (const float*)d_in[4];
  const float* cqw = (const float*)d_in[5];
  const float* cqb = (const float*)d_in[6];
  const float* ckw = (const float*)d_in[7];
  const float* ckb = (const float*)d_in[8];
  const float* lrw = (const float*)d_in[9];
  const float* lrb = (const float*)d_in[10];
  const float* lti = (const float*)d_in[11];
  const float* tns = (const float*)d_in[12];
  const float* tnb = (const float*)d_in[13];
  const float* pns = (const float*)d_in[14];
  const float* pnb = (const float*)d_in[15];
  const float* W1g = (const float*)d_in[16];
  const float* b1g = (const float*)d_in[17];
  float* out = (float*)d_out;

  char* ws = (char*)d_ws;
  __hip_bfloat16* xqk  = (__hip_bfloat16*)ws;
  __hip_bfloat16* xv   = xqk  + NELT;
  __hip_bfloat16* gate = xv   + NELT;
  __hip_bfloat16* xq   = gate + NELT;
  __hip_bfloat16* xk   = xq   + NELT;
  __hip_bfloat16* zb   = xk   + NELT;
  float* lrpre = (float*)(zb + NELT);
  float* st    = lrpre + (size_t)BB * NH * SSEQ;

  const dim3 gemmGrid((unsigned)(NTOK / 64), HIDDEN / 64);
  gemm_xw_bf16<<<gemmGrid, 256, 0, stream>>>(x, wq, xqk, 0);
  gemm_xw_bf16<<<gemmGrid, 256, 0, stream>>>(x, wv, xv, 0);
  gemm_xw_bf16<<<gemmGrid, 256, 0, stream>>>(x, wg, gate, 1);
  lrpre_kernel<<<(unsigned)(NTOK / 4), 256, 0, stream>>>(x, lrw, lrb, lrpre);
  convrope_kernel<<<(unsigned)(NTOK * 384 / 256), 256, 0, stream>>>(
      xqk, cqw, cqb, ckw, ckb, xq, xk);
  scan_mfma_kernel<<<BB * NH, 64, 0, stream>>>(xq, xk, xv, lrpre, lti, tns, tnb,
                                               W1g, b1g, zb);
  stats_kernel<<<(unsigned)(NTOK / 4), 256, 0, stream>>>(zb, st);
  gemm_out_kernel<<<gemmGrid, 256, 0, stream>>>(zb, gate, st, pns, pnb, wo, out);
}

// Round 4
// 2438.069 us; speedup vs baseline: 2.6239x; 1.8058x over previous
//
#include <hip/hip_runtime.h>
#include <hip/hip_bf16.h>
#include <math.h>

// Problem constants
#define BB 4
#define SSEQ 8192
#define HIDDEN 768
#define NH 12
#define DDIM 64
#define KMB 16
#define NMB 512
#define NTOK ((size_t)BB * SSEQ)          // 32768
#define NELT (NTOK * HIDDEN)              // 25,165,824
#define WELT (768 * 768)

typedef short bf16x8 __attribute__((ext_vector_type(8)));
typedef float f32x4 __attribute__((ext_vector_type(4)));

union frag_u {
  bf16x8 v;
  unsigned u32[4];
  unsigned short u16[8];
};

__device__ __forceinline__ f32x4 mfma16(bf16x8 a, bf16x8 b, f32x4 c) {
  return __builtin_amdgcn_mfma_f32_16x16x32_bf16(a, b, c, 0, 0, 0);
}

// ---------------- helpers ----------------
__device__ __forceinline__ float wave_sum(float v) {
#pragma unroll
  for (int off = 32; off > 0; off >>= 1) v += __shfl_xor(v, off, 64);
  return v;
}

// round-half-up bf16 (ties differ from RNE only on exact .5 ulp; negligible)
__device__ __forceinline__ unsigned short bf16hi(float x) {
  union { float f; unsigned u; } a; a.f = x;
  return (unsigned short)((a.u + 0x8000u) >> 16);
}
// pack two floats -> (bf16(f1)<<16)|bf16(f0) in 3 VALU ops via v_perm_b32
__device__ __forceinline__ unsigned pack_bf16(float f0, float f1) {
  union { float f; unsigned u; } a, b; a.f = f0; b.f = f1;
  return __builtin_amdgcn_perm(b.u + 0x8000u, a.u + 0x8000u, 0x07060302u);
}
__device__ __forceinline__ float bf2f(unsigned short s) {
  union { unsigned u; float f; } a; a.u = ((unsigned)s) << 16; return a.f;
}
__device__ __forceinline__ float gelu_tanh(float x) {
  float x3 = x * x * x;
  return 0.5f * x * (1.0f + tanhf(0.7978845608028654f * (x + 0.044715f * x3)));
}

__device__ __forceinline__ void glds16(const void* g, void* l) {
  __builtin_amdgcn_global_load_lds(
      (const __attribute__((address_space(1))) void*)g,
      (__attribute__((address_space(3))) void*)l, 16, 0, 0);
}

// ---------------- K0a: x (f32) -> xb (bf16) ----------------
__global__ __launch_bounds__(256) void cvt_x_kernel(
    const float* __restrict__ x, unsigned short* __restrict__ xb) {
  const size_t gid = (size_t)blockIdx.x * 256 + threadIdx.x;  // NELT/4
  const float4 v = *(const float4*)(x + gid * 4);
  uint2 r; r.x = pack_bf16(v.x, v.y); r.y = pack_bf16(v.z, v.w);
  *(uint2*)(xb + gid * 4) = r;
}

// ---------------- K0b: W (768x768 f32) -> W^T (768x768 bf16) ----------------
__global__ __launch_bounds__(256) void cvt_wT_kernel(
    const float* __restrict__ W, unsigned short* __restrict__ WT) {
  __shared__ float tile[32][33];
  const int tx = threadIdx.x & 31, ty = threadIdx.x >> 5;  // ty 0..7
  const int k0 = blockIdx.x * 32, n0 = blockIdx.y * 32;
#pragma unroll
  for (int r = 0; r < 4; ++r)
    tile[ty + 8 * r][tx] = W[(size_t)(k0 + ty + 8 * r) * 768 + n0 + tx];
  __syncthreads();
#pragma unroll
  for (int r = 0; r < 4; ++r)
    WT[(size_t)(n0 + ty + 8 * r) * 768 + k0 + tx] = bf16hi(tile[tx][ty + 8 * r]);
}

// ---------------- K1: MFMA GEMM  C[M,768] = A[M,768] @ BT[768,768]^T ------------
// m97 structure: 128x128 tile, BK=32, 256 thr (4 waves 2x2), global_load_lds w16.
// mode: 0 = bf16 out, 1 = bf16+gelu out, 2 = f32 out
__global__ __launch_bounds__(256) void gemm_mfma(
    const unsigned short* __restrict__ A, const unsigned short* __restrict__ BT,
    void* __restrict__ Cout, int mode) {
  __shared__ __align__(16) unsigned short Asl[128 * 32];
  __shared__ __align__(16) unsigned short Bsl[128 * 32];
  const int tid = threadIdx.x;
  const int wave = tid >> 6, lane = tid & 63;
  const int n16 = lane & 15, g16 = lane >> 4;
  const int wm = (wave >> 1) * 64, wn = (wave & 1) * 64;
  const int m0 = blockIdx.x * 128, n0 = blockIdx.y * 128;

  const int srow = tid >> 2;            // 0..63
  const int sseg = (tid & 3) * 8;       // k-element offset

  const unsigned short* aSrc0 = A + (size_t)(m0 + srow) * 768 + sseg;
  const unsigned short* aSrc1 = A + (size_t)(m0 + 64 + srow) * 768 + sseg;
  const unsigned short* bSrc0 = BT + (size_t)(n0 + srow) * 768 + sseg;
  const unsigned short* bSrc1 = BT + (size_t)(n0 + 64 + srow) * 768 + sseg;
  char* aDst0 = (char*)Asl + wave * 1024;
  char* aDst1 = (char*)Asl + 4096 + wave * 1024;
  char* bDst0 = (char*)Bsl + wave * 1024;
  char* bDst1 = (char*)Bsl + 4096 + wave * 1024;

  f32x4 acc[4][4];
#pragma unroll
  for (int i = 0; i < 4; ++i)
#pragma unroll
    for (int j = 0; j < 4; ++j) { acc[i][j][0] = 0.f; acc[i][j][1] = 0.f; acc[i][j][2] = 0.f; acc[i][j][3] = 0.f; }

  for (int k0 = 0; k0 < 768; k0 += 32) {
    __syncthreads();
    glds16(aSrc0 + k0, aDst0);
    glds16(aSrc1 + k0, aDst1);
    glds16(bSrc0 + k0, bDst0);
    glds16(bSrc1 + k0, bDst1);
    __syncthreads();
    bf16x8 af[4], bfr[4];
#pragma unroll
    for (int mf = 0; mf < 4; ++mf)
      af[mf] = *(const bf16x8*)(Asl + (wm + mf * 16 + n16) * 32 + g16 * 8);
#pragma unroll
    for (int nf = 0; nf < 4; ++nf)
      bfr[nf] = *(const bf16x8*)(Bsl + (wn + nf * 16 + n16) * 32 + g16 * 8);
#pragma unroll
    for (int mf = 0; mf < 4; ++mf)
#pragma unroll
      for (int nf = 0; nf < 4; ++nf)
        acc[mf][nf] = mfma16(af[mf], bfr[nf], acc[mf][nf]);
  }

  const int erow0 = m0 + wm + 4 * g16;
  const int ecol0 = n0 + wn + n16;
  if (mode == 2) {
    float* C = (float*)Cout;
#pragma unroll
    for (int mf = 0; mf < 4; ++mf)
#pragma unroll
      for (int nf = 0; nf < 4; ++nf)
#pragma unroll
        for (int r = 0; r < 4; ++r)
          C[(size_t)(erow0 + mf * 16 + r) * HIDDEN + ecol0 + nf * 16] = acc[mf][nf][r];
  } else if (mode == 1) {
    unsigned short* C = (unsigned short*)Cout;
#pragma unroll
    for (int mf = 0; mf < 4; ++mf)
#pragma unroll
      for (int nf = 0; nf < 4; ++nf)
#pragma unroll
        for (int r = 0; r < 4; ++r)
          C[(size_t)(erow0 + mf * 16 + r) * HIDDEN + ecol0 + nf * 16] = bf16hi(gelu_tanh(acc[mf][nf][r]));
  } else {
    unsigned short* C = (unsigned short*)Cout;
#pragma unroll
    for (int mf = 0; mf < 4; ++mf)
#pragma unroll
      for (int nf = 0; nf < 4; ++nf)
#pragma unroll
        for (int r = 0; r < 4; ++r)
          C[(size_t)(erow0 + mf * 16 + r) * HIDDEN + ecol0 + nf * 16] = bf16hi(acc[mf][nf][r]);
  }
}

// ---------------- K2: lrpre[b,h,s] = x[b,s,:]·lr_w[h,:] + lr_b[h] ----------------
__global__ __launch_bounds__(256) void lrpre_kernel(
    const float* __restrict__ x, const float* __restrict__ lrw,
    const float* __restrict__ lrb, float* __restrict__ lrpre) {
  const int g = threadIdx.x >> 6, l = threadIdx.x & 63;
  const int t = blockIdx.x * 4 + g;
  const float* xr = x + (size_t)t * HIDDEN;
  float xv[12];
#pragma unroll
  for (int j = 0; j < 12; ++j) xv[j] = xr[l + 64 * j];
  const int b = t >> 13, s = t & (SSEQ - 1);
  for (int h = 0; h < NH; ++h) {
    const float* wr = lrw + (size_t)h * HIDDEN;
    float a = 0.f;
#pragma unroll
    for (int j = 0; j < 12; ++j) a += xv[j] * wr[l + 64 * j];
    a = wave_sum(a);
    if (l == 0) lrpre[((size_t)b * NH + h) * SSEQ + s] = a + lrb[h];
  }
}

// ---------------- K3: conv (causal) + RoPE ----------------
__global__ __launch_bounds__(256) void convrope_kernel(
    const __hip_bfloat16* __restrict__ xqk,
    const float* __restrict__ cqw, const float* __restrict__ cqb,
    const float* __restrict__ ckw, const float* __restrict__ ckb,
    __hip_bfloat16* __restrict__ XQ, __hip_bfloat16* __restrict__ XK) {
  const size_t gid = (size_t)blockIdx.x * 256 + threadIdx.x;  // over NTOK*384
  const int p = (int)(gid % 384);
  const size_t bt = gid / 384;
  const int t = (int)(bt & (SSEQ - 1));
  const int c0 = 2 * p, c1 = c0 + 1;
  float q0 = cqb[c0], q1 = cqb[c1], k0v = ckb[c0], k1v = ckb[c1];
#pragma unroll
  for (int kk = 0; kk < 4; ++kk) {
    const int tp = t - 4 + kk;
    if (tp >= 0) {
      const size_t src = (bt - t + tp) * HIDDEN;
      const float x0 = __bfloat162float(xqk[src + c0]);
      const float x1 = __bfloat162float(xqk[src + c1]);
      q0  += cqw[kk * HIDDEN + c0] * x0;  q1  += cqw[kk * HIDDEN + c1] * x1;
      k0v += ckw[kk * HIDDEN + c0] * x0;  k1v += ckw[kk * HIDDEN + c1] * x1;
    }
  }
  const int f = p & 31;
  const float invf = expf(-(float)f * 0.28782313662425572f);  // ln(10000)/32
  const float ang = (float)t * invf;
  float sn, cs;
  sincosf(ang, &sn, &cs);
  const size_t o = bt * HIDDEN;
  XQ[o + c0] = __float2bfloat16(q0 * cs - q1 * sn);
  XQ[o + c1] = __float2bfloat16(q0 * sn + q1 * cs);
  XK[o + c0] = __float2bfloat16(k0v * cs - k1v * sn);
  XK[o + c1] = __float2bfloat16(k0v * sn + k1v * cs);
}

// ---------------- K4: single-wave MFMA TTT scan (see R3 notes) ----------------
struct ScanBuf {
  uint2 qa[2][2], ka[2][2];
  unsigned short kc[4][4], vc[4][4], qc[4][4];
  float lr[4];
};

__global__ __launch_bounds__(64) void scan_mfma_kernel(
    const __hip_bfloat16* __restrict__ XQg, const __hip_bfloat16* __restrict__ XKg,
    const __hip_bfloat16* __restrict__ XVg, const float* __restrict__ lrpre,
    const float* __restrict__ lti, const float* __restrict__ tnsg,
    const float* __restrict__ tnbg, const float* __restrict__ W1g,
    const float* __restrict__ b1g, __hip_bfloat16* __restrict__ Zg) {
  const int bh = blockIdx.x;
  const int b = bh / NH, h = bh % NH;
  const int lane = threadIdx.x;
  const int n = lane & 15, g16 = lane >> 4;
  const float inv64 = 1.0f / 64.0f;

  const unsigned short* XQb = (const unsigned short*)XQg + (size_t)b * SSEQ * HIDDEN + h * 64;
  const unsigned short* XKb = (const unsigned short*)XKg + (size_t)b * SSEQ * HIDDEN + h * 64;
  const unsigned short* XVb = (const unsigned short*)XVg + (size_t)b * SSEQ * HIDDEN + h * 64;
  unsigned short* Zb = (unsigned short*)Zg + (size_t)b * SSEQ * HIDDEN + h * 64;
  const float* lrp = lrpre + ((size_t)b * NH + h) * SSEQ;

  f32x4 W1acc[4][4];
#pragma unroll
  for (int db = 0; db < 4; ++db)
#pragma unroll
    for (int eb = 0; eb < 4; ++eb)
#pragma unroll
      for (int r = 0; r < 4; ++r)
        W1acc[db][eb][r] = W1g[(size_t)h * 4096 + (16 * db + 4 * g16 + r) * 64 + 16 * eb + n];

  float b1r[4], tnsr[4], tnbr[4];
#pragma unroll
  for (int eb = 0; eb < 4; ++eb) {
    const int e = h * 64 + 16 * eb + n;
    b1r[eb] = b1g[e]; tnsr[eb] = tnsg[e]; tnbr[eb] = tnbg[e];
  }
  const float tok_n = fmaxf(1.0f / (float)(n + 1) + lti[n], 0.0f);
  const float tok15 = __shfl(tok_n, 15, 64);

  int offA[2][2], offC[4][4];
#pragma unroll
  for (int c = 0; c < 2; ++c)
#pragma unroll
    for (int jg = 0; jg < 2; ++jg)
      offA[c][jg] = n * HIDDEN + 16 * (2 * c + jg) + 4 * g16;
#pragma unroll
  for (int blk = 0; blk < 4; ++blk)
#pragma unroll
    for (int r = 0; r < 4; ++r)
      offC[blk][r] = (4 * g16 + r) * HIDDEN + 16 * blk + n;

  auto load_mb = [&](ScanBuf& bf, int mb) {
    const size_t sb = (size_t)mb * (KMB * HIDDEN);
#pragma unroll
    for (int c = 0; c < 2; ++c)
#pragma unroll
      for (int jg = 0; jg < 2; ++jg) {
        bf.qa[c][jg] = *(const uint2*)(XQb + sb + offA[c][jg]);
        bf.ka[c][jg] = *(const uint2*)(XKb + sb + offA[c][jg]);
      }
#pragma unroll
    for (int blk = 0; blk < 4; ++blk)
#pragma unroll
      for (int r = 0; r < 4; ++r) {
        bf.kc[blk][r] = XKb[sb + offC[blk][r]];
        bf.vc[blk][r] = XVb[sb + offC[blk][r]];
        bf.qc[blk][r] = XQb[sb + offC[blk][r]];
      }
    const float4 l4 = *(const float4*)(lrp + mb * KMB + 4 * g16);
    bf.lr[0] = l4.x; bf.lr[1] = l4.y; bf.lr[2] = l4.z; bf.lr[3] = l4.w;
  };

  auto compute_mb = [&](ScanBuf& bf, int mb) {
    const size_t sb = (size_t)mb * (KMB * HIDDEN);
    float etaj[4];
#pragma unroll
    for (int jj = 0; jj < 4; ++jj)
      etaj[jj] = 1.0f / (64.0f * (1.0f + __expf(-bf.lr[jj])));

    // W1 -> bf16 B-frags via packed perm cvt
    frag_u w1f[2][4];
#pragma unroll
    for (int c = 0; c < 2; ++c)
#pragma unroll
      for (int eb = 0; eb < 4; ++eb) {
        w1f[c][eb].u32[0] = pack_bf16(W1acc[2 * c][eb][0], W1acc[2 * c][eb][1]);
        w1f[c][eb].u32[1] = pack_bf16(W1acc[2 * c][eb][2], W1acc[2 * c][eb][3]);
        w1f[c][eb].u32[2] = pack_bf16(W1acc[2 * c + 1][eb][0], W1acc[2 * c + 1][eb][1]);
        w1f[c][eb].u32[3] = pack_bf16(W1acc[2 * c + 1][eb][2], W1acc[2 * c + 1][eb][3]);
      }
    frag_u kaf[2], qaf[2];
#pragma unroll
    for (int c = 0; c < 2; ++c) {
      kaf[c].u32[0] = bf.ka[c][0].x; kaf[c].u32[1] = bf.ka[c][0].y;
      kaf[c].u32[2] = bf.ka[c][1].x; kaf[c].u32[3] = bf.ka[c][1].y;
      qaf[c].u32[0] = bf.qa[c][0].x; qaf[c].u32[1] = bf.qa[c][0].y;
      qaf[c].u32[2] = bf.qa[c][1].x; qaf[c].u32[3] = bf.qa[c][1].y;
    }
    f32x4 zk[4], zq[4];
#pragma unroll
    for (int eb = 0; eb < 4; ++eb) {
      f32x4 init; init[0] = b1r[eb]; init[1] = b1r[eb]; init[2] = b1r[eb]; init[3] = b1r[eb];
      zk[eb] = init; zq[eb] = init;
    }
#pragma unroll
    for (int c = 0; c < 2; ++c)
#pragma unroll
      for (int eb = 0; eb < 4; ++eb) {
        zk[eb] = mfma16(kaf[c].v, w1f[c][eb].v, zk[eb]);
        zq[eb] = mfma16(qaf[c].v, w1f[c][eb].v, zq[eb]);
      }
    f32x4 st_; st_[0] = 0.f; st_[1] = 0.f; st_[2] = 0.f; st_[3] = 0.f;
    st_ = mfma16(kaf[0].v, qaf[0].v, st_);
    st_ = mfma16(kaf[1].v, qaf[1].v, st_);

    float s1[4], s2[4];
#pragma unroll
    for (int r = 0; r < 4; ++r) {
      s1[r] = zk[0][r] + zk[1][r] + zk[2][r] + zk[3][r];
      s2[r] = zk[0][r] * zk[0][r] + zk[1][r] * zk[1][r] + zk[2][r] * zk[2][r] + zk[3][r] * zk[3][r];
    }
#pragma unroll
    for (int off = 1; off < 16; off <<= 1)
#pragma unroll
      for (int r = 0; r < 4; ++r) {
        s1[r] += __shfl_xor(s1[r], off, 64);
        s2[r] += __shfl_xor(s2[r], off, 64);
      }
    float mr[4], rstd[4];
#pragma unroll
    for (int r = 0; r < 4; ++r) {
      mr[r] = s1[r] * inv64;
      rstd[r] = rsqrtf(s2[r] * inv64 - mr[r] * mr[r] + 1e-5f);
    }
    float xh[4][4], gx[4][4], t1[4] = {0.f, 0.f, 0.f, 0.f}, t2[4] = {0.f, 0.f, 0.f, 0.f};
#pragma unroll
    for (int eb = 0; eb < 4; ++eb)
#pragma unroll
      for (int r = 0; r < 4; ++r) {
        const float xh_ = (zk[eb][r] - mr[r]) * rstd[r];
        const float tg = bf2f(bf.vc[eb][r]) - bf2f(bf.kc[eb][r]);
        const float gx_ = (xh_ * tnsr[eb] + tnbr[eb] - tg) * tnsr[eb];
        xh[eb][r] = xh_; gx[eb][r] = gx_;
        t1[r] += gx_; t2[r] += gx_ * xh_;
      }
#pragma unroll
    for (int off = 1; off < 16; off <<= 1)
#pragma unroll
      for (int r = 0; r < 4; ++r) {
        t1[r] += __shfl_xor(t1[r], off, 64);
        t2[r] += __shfl_xor(t2[r], off, 64);
      }
    float g_[4][4];
#pragma unroll
    for (int eb = 0; eb < 4; ++eb)
#pragma unroll
      for (int r = 0; r < 4; ++r)
        g_[eb][r] = (gx[eb][r] - t1[r] * inv64 - xh[eb][r] * (t2[r] * inv64)) * rstd[r];

    frag_u gbf[4];
#pragma unroll
    for (int eb = 0; eb < 4; ++eb) {
      gbf[eb].u32[0] = pack_bf16(g_[eb][0], g_[eb][1]);
      gbf[eb].u32[1] = pack_bf16(g_[eb][2], g_[eb][3]);
      gbf[eb].u32[2] = 0; gbf[eb].u32[3] = 0;
    }
    frag_u coef;
    {
      float cf[4];
#pragma unroll
      for (int jj = 0; jj < 4; ++jj) {
        const int j = 4 * g16 + jj;
        cf[jj] = (j <= n) ? -tok_n * etaj[jj] * (1.0f + st_[jj]) : 0.0f;
      }
      coef.u32[0] = pack_bf16(cf[0], cf[1]);
      coef.u32[1] = pack_bf16(cf[2], cf[3]);
      coef.u32[2] = 0; coef.u32[3] = 0;
    }
    f32x4 zbv[4];
#pragma unroll
    for (int eb = 0; eb < 4; ++eb)
      zbv[eb] = mfma16(coef.v, gbf[eb].v, zq[eb]);

#pragma unroll
    for (int r = 0; r < 4; ++r) {
      s1[r] = zbv[0][r] + zbv[1][r] + zbv[2][r] + zbv[3][r];
      s2[r] = zbv[0][r] * zbv[0][r] + zbv[1][r] * zbv[1][r] + zbv[2][r] * zbv[2][r] + zbv[3][r] * zbv[3][r];
    }
#pragma unroll
    for (int off = 1; off < 16; off <<= 1)
#pragma unroll
      for (int r = 0; r < 4; ++r) {
        s1[r] += __shfl_xor(s1[r], off, 64);
        s2[r] += __shfl_xor(s2[r], off, 64);
      }
#pragma unroll
    for (int r = 0; r < 4; ++r) {
      mr[r] = s1[r] * inv64;
      rstd[r] = rsqrtf(s2[r] * inv64 - mr[r] * mr[r] + 1e-5f);
    }
#pragma unroll
    for (int eb = 0; eb < 4; ++eb)
#pragma unroll
      for (int r = 0; r < 4; ++r) {
        const float o = bf2f(bf.qc[eb][r]) + (zbv[eb][r] - mr[r]) * rstd[r] * tnsr[eb] + tnbr[eb];
        Zb[sb + offC[eb][r]] = bf16hi(o);
      }

    float lgv[4][4];
    frag_u lgf[4], ktf[4];
#pragma unroll
    for (int eb = 0; eb < 4; ++eb) {
#pragma unroll
      for (int jj = 0; jj < 4; ++jj) lgv[eb][jj] = -tok15 * etaj[jj] * g_[eb][jj];
      lgf[eb].u32[0] = pack_bf16(lgv[eb][0], lgv[eb][1]);
      lgf[eb].u32[1] = pack_bf16(lgv[eb][2], lgv[eb][3]);
      lgf[eb].u32[2] = 0; lgf[eb].u32[3] = 0;
    }
#pragma unroll
    for (int mk = 0; mk < 4; ++mk) {
      ktf[mk].u32[0] = (unsigned)bf.kc[mk][0] | ((unsigned)bf.kc[mk][1] << 16);
      ktf[mk].u32[1] = (unsigned)bf.kc[mk][2] | ((unsigned)bf.kc[mk][3] << 16);
      ktf[mk].u32[2] = 0; ktf[mk].u32[3] = 0;
    }
#pragma unroll
    for (int mk = 0; mk < 4; ++mk)
#pragma unroll
      for (int eb = 0; eb < 4; ++eb)
        W1acc[mk][eb] = mfma16(ktf[mk].v, lgf[eb].v, W1acc[mk][eb]);
#pragma unroll
    for (int eb = 0; eb < 4; ++eb) {
      float s = lgv[eb][0] + lgv[eb][1] + lgv[eb][2] + lgv[eb][3];
      s += __shfl_xor(s, 16, 64);
      s += __shfl_xor(s, 32, 64);
      b1r[eb] += s;
    }
  };

  ScanBuf A, B;
  load_mb(A, 0);
  for (int mb = 0; mb < NMB; mb += 2) {
    load_mb(B, mb + 1);
    compute_mb(A, mb);
    if (mb + 2 < NMB) load_mb(A, mb + 2);
    compute_mb(B, mb + 1);
  }
}

// ---------------- K5: per-token mean/rstd over 768 ----------------
__global__ __launch_bounds__(256) void stats_kernel(
    const __hip_bfloat16* __restrict__ Z, float* __restrict__ st) {
  const int g = threadIdx.x >> 6, l = threadIdx.x & 63;
  const int t = blockIdx.x * 4 + g;
  const __hip_bfloat16* zr = Z + (size_t)t * HIDDEN;
  float zv[12];
  float s_ = 0.f;
#pragma unroll
  for (int j = 0; j < 12; ++j) { zv[j] = __bfloat162float(zr[l + 64 * j]); s_ += zv[j]; }
  s_ = wave_sum(s_);
  const float m = s_ * (1.0f / 768.0f);
  float v_ = 0.f;
#pragma unroll
  for (int j = 0; j < 12; ++j) { const float d = zv[j] - m; v_ += d * d; }
  v_ = wave_sum(v_) * (1.0f / 768.0f);
  if (l == 0) { st[2 * t] = m; st[2 * t + 1] = rsqrtf(v_ + 1e-5f); }
}

// ---------------- K5b: aout = ((Z-mu)*rstd*pns + pnb)*gate  (bf16) ----------------
__global__ __launch_bounds__(256) void fuse_epi_kernel(
    const unsigned short* __restrict__ Zb, const unsigned short* __restrict__ gateb,
    const float* __restrict__ st, const float* __restrict__ pns,
    const float* __restrict__ pnb, unsigned short* __restrict__ aout) {
  const int gid = blockIdx.x * 256 + threadIdx.x;  // NELT/4 threads
  const int t = gid / 192;
  const int c = (gid - t * 192) * 4;
  const float mu = st[2 * t], rstd = st[2 * t + 1];
  const size_t base = (size_t)t * HIDDEN + c;
  const uint2 z2 = *(const uint2*)(Zb + base);
  const uint2 g2 = *(const uint2*)(gateb + base);
  const float4 p4 = *(const float4*)(pns + c);
  const float4 q4 = *(const float4*)(pnb + c);
  const float o0 = ((bf2f((unsigned short)(z2.x & 0xffff)) - mu) * rstd * p4.x + q4.x) * bf2f((unsigned short)(g2.x & 0xffff));
  const float o1 = ((bf2f((unsigned short)(z2.x >> 16)) - mu) * rstd * p4.y + q4.y) * bf2f((unsigned short)(g2.x >> 16));
  const float o2 = ((bf2f((unsigned short)(z2.y & 0xffff)) - mu) * rstd * p4.z + q4.z) * bf2f((unsigned short)(g2.y & 0xffff));
  const float o3 = ((bf2f((unsigned short)(z2.y >> 16)) - mu) * rstd * p4.w + q4.w) * bf2f((unsigned short)(g2.y >> 16));
  uint2 r; r.x = pack_bf16(o0, o1); r.y = pack_bf16(o2, o3);
  *(uint2*)(aout + base) = r;
}

// ---------------- launch ----------------
extern "C" void kernel_launch(void* const* d_in, const int* in_sizes, int n_in,
                              void* d_out, int out_size, void* d_ws, size_t ws_size,
                              hipStream_t stream) {
  const float* x   = (const float*)d_in[0];
  const float* wq  = (const float*)d_in[1];
  const float* wv  = (const float*)d_in[2];
  const float* wo  = (const float*)d_in[3];
  const float* wg  = (const float*)d_in[4];
  const float* cqw = (const float*)d_in[5];
  const float* cqb = (const float*)d_in[6];
  const float* ckw = (const float*)d_in[7];
  const float* ckb = (const float*)d_in[8];
  const float* lrw = (const float*)d_in[9];
  const float* lrb = (const float*)d_in[10];
  const float* lti = (const float*)d_in[11];
  const float* tns = (const float*)d_in[12];
  const float* tnb = (const float*)d_in[13];
  const float* pns = (const float*)d_in[14];
  const float* pnb = (const float*)d_in[15];
  const float* W1g = (const float*)d_in[16];
  const float* b1g = (const float*)d_in[17];
  float* out = (float*)d_out;

  // ws layout (bf16 slots, with aliasing): total ~309 MB
  unsigned short* zbuf = (unsigned short*)d_ws;    // slot0: xb (pre-scan) / zb (post-scan)
  unsigned short* xqk  = zbuf + NELT;              // slot1: xqk / aout
  unsigned short* xv   = xqk + NELT;
  unsigned short* gate = xv + NELT;
  unsigned short* xq   = gate + NELT;
  unsigned short* xk   = xq + NELT;
  unsigned short* wqT  = xk + NELT;
  unsigned short* wvT  = wqT + WELT;
  unsigned short* wgT  = wvT + WELT;
  unsigned short* woT  = wgT + WELT;
  float* lrpre = (float*)(woT + WELT);
  float* st    = lrpre + (size_t)BB * NH * SSEQ;
  unsigned short* xb   = zbuf;
  unsigned short* aout = xqk;

  const dim3 wtGrid(24, 24);
  cvt_x_kernel<<<(unsigned)(NELT / 4 / 256), 256, 0, stream>>>(x, xb);
  cvt_wT_kernel<<<wtGrid, 256, 0, stream>>>(wq, wqT);
  cvt_wT_kernel<<<wtGrid, 256, 0, stream>>>(wv, wvT);
  cvt_wT_kernel<<<wtGrid, 256, 0, stream>>>(wg, wgT);
  cvt_wT_kernel<<<wtGrid, 256, 0, stream>>>(wo, woT);

  const dim3 gemmGrid((unsigned)(NTOK / 128), HIDDEN / 128);
  gemm_mfma<<<gemmGrid, 256, 0, stream>>>(xb, wqT, (void*)xqk, 0);
  gemm_mfma<<<gemmGrid, 256, 0, stream>>>(xb, wvT, (void*)xv, 0);
  gemm_mfma<<<gemmGrid, 256, 0, stream>>>(xb, wgT, (void*)gate, 1);
  lrpre_kernel<<<(unsigned)(NTOK / 4), 256, 0, stream>>>(x, lrw, lrb, lrpre);
  convrope_kernel<<<(unsigned)(NTOK * 384 / 256), 256, 0, stream>>>(
      (const __hip_bfloat16*)xqk, cqw, cqb, ckw, ckb,
      (__hip_bfloat16*)xq, (__hip_bfloat16*)xk);
  scan_mfma_kernel<<<BB * NH, 64, 0, stream>>>(
      (const __hip_bfloat16*)xq, (const __hip_bfloat16*)xk,
      (const __hip_bfloat16*)xv, lrpre, lti, tns, tnb, W1g, b1g,
      (__hip_bfloat16*)zbuf);
  stats_kernel<<<(unsigned)(NTOK / 4), 256, 0, stream>>>((const __hip_bfloat16*)zbuf, st);
  fuse_epi_kernel<<<(unsigned)(NELT / 4 / 256), 256, 0, stream>>>(zbuf, gate, st, pns, pnb, aout);
  gemm_mfma<<<gemmGrid, 256, 0, stream>>>(aout, woT, (void*)out, 2);
}